// Round 6
// baseline (447.626 us; speedup 1.0000x reference)
//
#include <hip/hip_runtime.h>
#include <hip/hip_fp16.h>
#include <math.h>

#define NN   50000
#define INF_ 256
#define HID  64
#define OUTF 32
#define EE   800000
#define TOTN (3 * NN)
#define GB   782          // gemm blocks per branch: ceil(50000/64)
#define HB   3125         // hist blocks per branch: 800000/256
#define NHIST (3 * HB)    // 9375 hist blocks first
#define MASK40 ((1ULL << 40) - 1)

typedef unsigned long long u64;
typedef unsigned int       u32;
typedef unsigned short     u16;

// ---------------- init: packed hist = 0, total = 0 ----------------
__global__ __launch_bounds__(256) void k_init(u64* __restrict__ packed, int* __restrict__ total) {
    int i = blockIdx.x * 256 + threadIdx.x;
    if (i < TOTN) packed[i] = 0ULL;
    if (i == 0) *total = 0;
}

// ---------------- fused: histogram FIRST (atomic, returns rank), then layer-1 GEMM ----------------
// 1D grid: bid < NHIST -> 256-edge hist chunk; else gemm tile (64x64, BK=32).
__global__ __launch_bounds__(256) void k_histgemm(
        const int* __restrict__ ei1, const int* __restrict__ ei2, const int* __restrict__ ei3,
        const float* __restrict__ ew1, const float* __restrict__ ew2, const float* __restrict__ ew3,
        u64* __restrict__ packed, u16* __restrict__ rank,
        const float* __restrict__ x1, const float* __restrict__ x2, const float* __restrict__ x3,
        const float* __restrict__ W1, const float* __restrict__ W2, const float* __restrict__ W3,
        __half* __restrict__ h) {
    __shared__ float xs[64][36];    // 9.2 KB
    __shared__ float Ws[32][68];    // 8.7 KB  -> 17.9 KB total
    int bid = blockIdx.x;

    if (bid < NHIST) {              // ---- hist part: issued first ----
        int b = bid / HB;
        int chunk = bid - b * HB;
        const int*   ei = (b == 0) ? ei1 : (b == 1) ? ei2 : ei3;
        const float* ew = (b == 0) ? ew1 : (b == 1) ? ew2 : ew3;
        int e = chunk * 256 + threadIdx.x;           // HB*256 == EE exact
        int dst = ei[EE + e];
        u64 contrib = (1ULL << 40) | (u64)(u32)(ew[e] * 16777216.0f);
        u64 old = atomicAdd(&packed[b * NN + dst], contrib);
        rank[(size_t)b * EE + e] = (u16)(old >> 40);
        return;
    }

    // ---- gemm part: h = x @ W (fp16 out) ----
    int g = bid - NHIST;
    int b = g / GB;
    int row_base = (g - b * GB) * 64;
    const float* x = (b == 0) ? x1 : (b == 1) ? x2 : x3;
    const float* W = (b == 0) ? W1 : (b == 1) ? W2 : W3;
    __half* hb = h + (size_t)b * NN * HID;

    int t  = threadIdx.x;
    int tx = t & 15;
    int ty = t >> 4;

    float acc[4][4] = {};
    const float4* x4 = reinterpret_cast<const float4*>(x);
    const float4* W4 = reinterpret_cast<const float4*>(W);
    for (int kt = 0; kt < INF_ / 32; ++kt) {
#pragma unroll
        for (int j = 0; j < 2; ++j) {               // stage x: 512 float4
            int flat = t + j * 256;
            int r = flat >> 3, c4 = flat & 7;
            int gr = row_base + r;
            float4 v = (gr < NN)
                ? x4[(size_t)gr * (INF_ / 4) + kt * 8 + c4]
                : make_float4(0.f, 0.f, 0.f, 0.f);
            *reinterpret_cast<float4*>(&xs[r][c4 * 4]) = v;
        }
#pragma unroll
        for (int j = 0; j < 2; ++j) {               // stage W: 512 float4
            int flat = t + j * 256;
            int r = flat >> 4, c4 = flat & 15;
            *reinterpret_cast<float4*>(&Ws[r][c4 * 4]) = W4[(kt * 32 + r) * 16 + c4];
        }
        __syncthreads();
#pragma unroll
        for (int k = 0; k < 32; ++k) {
            float4 wv = *reinterpret_cast<const float4*>(&Ws[k][tx * 4]);
            float xv[4];
#pragma unroll
            for (int i = 0; i < 4; ++i) xv[i] = xs[ty * 4 + i][k];
#pragma unroll
            for (int i = 0; i < 4; ++i) {
                acc[i][0] = fmaf(xv[i], wv.x, acc[i][0]);
                acc[i][1] = fmaf(xv[i], wv.y, acc[i][1]);
                acc[i][2] = fmaf(xv[i], wv.z, acc[i][2]);
                acc[i][3] = fmaf(xv[i], wv.w, acc[i][3]);
            }
        }
        __syncthreads();
    }
#pragma unroll
    for (int i = 0; i < 4; ++i) {
        int row = row_base + ty * 4 + i;
        if (row < NN) {
            ushort4 v;
            v.x = __half_as_ushort(__float2half(acc[i][0]));
            v.y = __half_as_ushort(__float2half(acc[i][1]));
            v.z = __half_as_ushort(__float2half(acc[i][2]));
            v.w = __half_as_ushort(__float2half(acc[i][3]));
            *reinterpret_cast<ushort4*>(&hb[(size_t)row * HID + tx * 4]) = v;
        }
    }
}

// ---------------- offsets: unpack packed -> cnt/dinv, block scan -> start ----------------
__global__ __launch_bounds__(256) void k_offsets(const u64* __restrict__ packed,
                                                 int* __restrict__ cnt, float* __restrict__ dinv,
                                                 int* __restrict__ start, int* __restrict__ total) {
    __shared__ int s[256];
    __shared__ int s_base;
    int t = threadIdx.x;
    int base_i = blockIdx.x * 1024 + t * 4;
    int c[4]; int sum = 0;
#pragma unroll
    for (int k = 0; k < 4; ++k) {
        int i = base_i + k;
        if (i < TOTN) {
            u64 p = packed[i];
            c[k] = (int)(p >> 40);
            cnt[i] = c[k];
            dinv[i] = rsqrtf(1.0f + (float)(p & MASK40) * (1.0f / 16777216.0f));
        } else c[k] = 0;
        sum += c[k];
    }
    s[t] = sum;
    __syncthreads();
    for (int d = 1; d < 256; d <<= 1) {
        int v = (t >= d) ? s[t - d] : 0;
        __syncthreads();
        s[t] += v;
        __syncthreads();
    }
    if (t == 255) s_base = atomicAdd(total, s[255]);
    __syncthreads();
    int run = s_base + s[t] - sum;
#pragma unroll
    for (int k = 0; k < 4; ++k) {
        int i = base_i + k;
        if (i < TOTN) start[i] = run;
        run += c[k];
    }
}

// ---------------- fill CSR (atomic-free): csr[start+rank] = fp16(dinv_src*w)<<16 | src ----------------
__global__ __launch_bounds__(256) void k_fill(
        const int* __restrict__ ei1, const int* __restrict__ ei2, const int* __restrict__ ei3,
        const float* __restrict__ ew1, const float* __restrict__ ew2, const float* __restrict__ ew3,
        const float* __restrict__ dinv, const int* __restrict__ start,
        const u16* __restrict__ rank, u32* __restrict__ csr) {
    int b = blockIdx.y;
    const int*   ei = (b == 0) ? ei1 : (b == 1) ? ei2 : ei3;
    const float* ew = (b == 0) ? ew1 : (b == 1) ? ew2 : ew3;
    int e = blockIdx.x * 256 + threadIdx.x;
    int src = ei[e];
    int dst = ei[EE + e];
    float normp = dinv[b * NN + src] * ew[e];        // dinv[dst] applied at aggregation
    int pos = start[b * NN + dst] + (int)rank[(size_t)b * EE + e];
    csr[pos] = ((u32)__half_as_ushort(__float2half(normp)) << 16) | (u32)src;
}

// ---------------- fused: layer-1 aggregation (3 branches) + attention + layer-2 GEMM ----------------
__global__ __launch_bounds__(256) void k_agg_attn(
        const u32* __restrict__ csr, const int* __restrict__ start, const int* __restrict__ cnt,
        const float* __restrict__ dinv,
        const float* __restrict__ b1, const float* __restrict__ b2, const float* __restrict__ b3,
        const __half* __restrict__ h,
        const float* __restrict__ fc_w, const float* __restrict__ fc_b,
        const float* __restrict__ W11, const float* __restrict__ W22, const float* __restrict__ W33,
        __half* __restrict__ h2, float* __restrict__ coef_out) {
    __shared__ float Wls[3][HID][OUTF];   // 24 KB
    __shared__ float cls[4][HID];         // 1 KB: combined rows for this block's 4 nodes
    int t = threadIdx.x;

    {   // stage layer-2 weights (used after the agg phase)
        const float4* w40 = reinterpret_cast<const float4*>(W11);
        const float4* w41 = reinterpret_cast<const float4*>(W22);
        const float4* w42 = reinterpret_cast<const float4*>(W33);
        float4* d0 = reinterpret_cast<float4*>(&Wls[0][0][0]);
        float4* d1 = reinterpret_cast<float4*>(&Wls[1][0][0]);
        float4* d2 = reinterpret_cast<float4*>(&Wls[2][0][0]);
#pragma unroll
        for (int j = 0; j < 2; ++j) {
            d0[t + j * 256] = w40[t + j * 256];
            d1[t + j * 256] = w41[t + j * 256];
            d2[t + j * 256] = w42[t + j * 256];
        }
    }

    int f   = t & 63;
    int sub = __builtin_amdgcn_readfirstlane(t >> 6);
    int n   = blockIdx.x * 4 + sub;                  // 50000 = 12500*4 exact
    float wv = fc_w[f];
    float fb = fc_b[0];

    float ev[3], c[3];
#pragma unroll
    for (int b = 0; b < 3; ++b) {
        const float* bi = (b == 0) ? b1 : (b == 1) ? b2 : b3;
        const __half* hb = h + (size_t)b * NN * HID;
        int i  = b * NN + n;
        int cc = cnt[i];
        int st = start[i];
        float d = dinv[i];
        float hs = __half2float(hb[(size_t)n * HID + f]);

        float ssum = 0.f;
        int j = 0;
        for (; j + 4 <= cc; j += 4) {
            u32 e0 = csr[st + j],     e1 = csr[st + j + 1];
            u32 e2 = csr[st + j + 2], e3 = csr[st + j + 3];
            float v0 = __half2float(hb[(size_t)(e0 & 0xffff) * HID + f]);
            float v1 = __half2float(hb[(size_t)(e1 & 0xffff) * HID + f]);
            float v2 = __half2float(hb[(size_t)(e2 & 0xffff) * HID + f]);
            float v3 = __half2float(hb[(size_t)(e3 & 0xffff) * HID + f]);
            ssum = fmaf(__half2float(__ushort_as_half((u16)(e0 >> 16))), v0, ssum);
            ssum = fmaf(__half2float(__ushort_as_half((u16)(e1 >> 16))), v1, ssum);
            ssum = fmaf(__half2float(__ushort_as_half((u16)(e2 >> 16))), v2, ssum);
            ssum = fmaf(__half2float(__ushort_as_half((u16)(e3 >> 16))), v3, ssum);
        }
        for (; j < cc; ++j) {
            u32 e0 = csr[st + j];
            ssum = fmaf(__half2float(__ushort_as_half((u16)(e0 >> 16))),
                        __half2float(hb[(size_t)(e0 & 0xffff) * HID + f]), ssum);
        }
        float acc = bi[f] + d * d * hs + d * ssum;
        ev[b] = fmaxf(acc, 0.f);                     // ReLU

        float dd = ev[b] * wv;
#pragma unroll
        for (int off = 32; off > 0; off >>= 1) dd += __shfl_xor(dd, off);
        float z = dd + fb;
        z = (z > 0.f) ? z : 0.01f * z;
        c[b] = expf(z);
    }
    float cd = c[0] + c[1] + c[2];
    float coef0 = c[0] / cd, coef1 = c[1] / cd, coef2 = c[2] / cd;
    cls[sub][f] = ev[0] * coef0 + ev[1] * coef1 + ev[2] * coef2;
    if (f == 0) {
        coef_out[n]          = coef0;
        coef_out[NN + n]     = coef1;
        coef_out[2 * NN + n] = coef2;
    }
    __syncthreads();

    // ---- layer-2 GEMM for this block's 4 nodes: 4 nodes x 3 branches x 32 cols ----
    for (int idx = t; idx < 384; idx += 256) {
        int node = idx / 96;
        int rem  = idx - node * 96;
        int br   = rem >> 5;
        int col  = rem & 31;
        float a = 0.f;
#pragma unroll
        for (int k = 0; k < HID; ++k)
            a = fmaf(cls[node][k], Wls[br][k][col], a);
        h2[(size_t)br * NN * OUTF + (size_t)(blockIdx.x * 4 + node) * OUTF + col] = __float2half(a);
    }
}

// ---------------- layer-2 aggregation: one wave per node, all 3 branches ----------------
__global__ __launch_bounds__(256) void k_agg2(
        const u32* __restrict__ csr, const int* __restrict__ start, const int* __restrict__ cnt,
        const float* __restrict__ dinv,
        const float* __restrict__ b11, const float* __restrict__ b22, const float* __restrict__ b33,
        const __half* __restrict__ h2, float* __restrict__ out) {
    int f    = threadIdx.x & 31;
    int half = (threadIdx.x >> 5) & 1;
    int sub  = __builtin_amdgcn_readfirstlane(threadIdx.x >> 6);
    int n    = blockIdx.x * 4 + sub;

    float tot = b11[f] + b22[f] + b33[f];
#pragma unroll
    for (int b = 0; b < 3; ++b) {
        int i  = b * NN + n;
        int cc = cnt[i];
        int st = start[i];
        const __half* h2b = h2 + (size_t)b * NN * OUTF;
        float accb = 0.f;
        for (int j = half; j < cc; j += 2) {
            u32 e0 = csr[st + j];
            accb = fmaf(__half2float(__ushort_as_half((u16)(e0 >> 16))),
                        __half2float(h2b[(size_t)(e0 & 0xffff) * OUTF + f]), accb);
        }
        accb += __shfl_xor(accb, 32);
        float d = dinv[i];
        tot += d * accb + d * d * __half2float(h2b[(size_t)n * OUTF + f]);
    }
    if (half == 0) out[(size_t)n * OUTF + f] = tot;
}

// ---------------- launch ----------------
extern "C" void kernel_launch(void* const* d_in, const int* in_sizes, int n_in,
                              void* d_out, int out_size, void* d_ws, size_t ws_size,
                              hipStream_t stream) {
    const float* x1  = (const float*)d_in[0];
    const float* x2  = (const float*)d_in[1];
    const float* x3  = (const float*)d_in[2];
    const int*   ei1 = (const int*)d_in[3];
    const int*   ei2 = (const int*)d_in[4];
    const int*   ei3 = (const int*)d_in[5];
    const float* ew1 = (const float*)d_in[6];
    const float* ew2 = (const float*)d_in[7];
    const float* ew3 = (const float*)d_in[8];
    const float* W1  = (const float*)d_in[9];
    const float* W2  = (const float*)d_in[10];
    const float* W3  = (const float*)d_in[11];
    const float* b1  = (const float*)d_in[12];
    const float* b2  = (const float*)d_in[13];
    const float* b3  = (const float*)d_in[14];
    const float* fcw = (const float*)d_in[15];
    const float* fcb = (const float*)d_in[16];
    const float* W11 = (const float*)d_in[17];
    const float* W22 = (const float*)d_in[18];
    const float* W33 = (const float*)d_in[19];
    const float* b11 = (const float*)d_in[20];
    const float* b22 = (const float*)d_in[21];
    const float* b33 = (const float*)d_in[22];

    float* out = (float*)d_out;
    float* coef_out = out + (size_t)NN * OUTF;

    // workspace layout (descending alignment)
    u64*   packed = (u64*)d_ws;                            // 3N u64      1.2 MB
    u32*   csr    = (u32*)(packed + TOTN);                 // 3E u32      9.6 MB
    u16*   rank   = (u16*)(csr + 3 * EE);                  // 3E u16      4.8 MB
    float* dinv   = (float*)(rank + 3 * EE);               // 3N f32
    int*   cnt    = (int*)(dinv + TOTN);                   // 3N
    int*   start  = cnt + TOTN;                            // 3N
    int*   total  = start + TOTN;                          // 64 pad
    __half* h     = (__half*)(total + 64);                 // 3N*64 fp16  19.2 MB
    __half* h2    = h + (size_t)TOTN * HID;                // 3N*32 fp16   9.6 MB

    k_init<<<dim3((TOTN + 255) / 256), 256, 0, stream>>>(packed, total);
    k_histgemm<<<dim3(NHIST + 3 * GB), 256, 0, stream>>>(ei1, ei2, ei3, ew1, ew2, ew3,
                                                         packed, rank,
                                                         x1, x2, x3, W1, W2, W3, h);
    k_offsets<<<dim3((TOTN + 1023) / 1024), 256, 0, stream>>>(packed, cnt, dinv, start, total);
    k_fill<<<dim3(EE / 256, 3), 256, 0, stream>>>(ei1, ei2, ei3, ew1, ew2, ew3,
                                                  dinv, start, rank, csr);

    k_agg_attn<<<dim3(NN / 4), 256, 0, stream>>>(csr, start, cnt, dinv, b1, b2, b3,
                                                 h, fcw, fcb, W11, W22, W33, h2, coef_out);
    k_agg2<<<dim3(NN / 4), 256, 0, stream>>>(csr, start, cnt, dinv,
                                             b11, b22, b33, h2, out);
}

// Round 7
// 355.667 us; speedup vs baseline: 1.2586x; 1.2586x over previous
//
#include <hip/hip_runtime.h>
#include <hip/hip_fp16.h>
#include <math.h>

#define NN   50000
#define INF_ 256
#define HID  64
#define OUTF 32
#define EE   800000
#define TOTN (3 * NN)
#define GB   782          // gemm tiles per branch: ceil(50000/64)
#define HB   3125         // hist chunks per branch: 800000/256
#define NHIST (3 * HB)    // 9375
#define NGEMM (3 * GB)    // 2346
#define MASK40 ((1ULL << 40) - 1)

typedef unsigned long long u64;
typedef unsigned int       u32;
typedef unsigned short     u16;

// ---------------- init: packed hist = 0, total = 0 ----------------
__global__ __launch_bounds__(256) void k_init(u64* __restrict__ packed, int* __restrict__ total) {
    int i = blockIdx.x * 256 + threadIdx.x;
    if (i < TOTN) packed[i] = 0ULL;
    if (i == 0) *total = 0;
}

// ---------------- fused hist+gemm, uniform 1:4 interleave (gemm at bid%5==0) ----------------
// Heterogeneous co-residency: every resident window mixes compute-bound gemm waves
// with atomic-bound hist waves (R6 showed phase-separation costs +50us).
__global__ __launch_bounds__(256) void k_histgemm(
        const int* __restrict__ ei1, const int* __restrict__ ei2, const int* __restrict__ ei3,
        const float* __restrict__ ew1, const float* __restrict__ ew2, const float* __restrict__ ew3,
        u64* __restrict__ packed, u16* __restrict__ rank,
        const float* __restrict__ x1, const float* __restrict__ x2, const float* __restrict__ x3,
        const float* __restrict__ W1, const float* __restrict__ W2, const float* __restrict__ W3,
        __half* __restrict__ h) {
    __shared__ float xs[64][36];    // 9.2 KB
    __shared__ float Ws[32][68];    // 8.7 KB  -> 17.9 KB total, 8 blocks/CU
    int bid = blockIdx.x;
    int q = bid / 5, r = bid - q * 5;

    if (r != 0) {                   // ---- hist: 4 of every 5 blocks ----
        int hid = q * 4 + r - 1;
        if (hid >= NHIST) return;
        int b = hid / HB;
        int chunk = hid - b * HB;
        const int*   ei = (b == 0) ? ei1 : (b == 1) ? ei2 : ei3;
        const float* ew = (b == 0) ? ew1 : (b == 1) ? ew2 : ew3;
        int e = chunk * 256 + threadIdx.x;           // HB*256 == EE exact
        int dst = ei[EE + e];
        u64 contrib = (1ULL << 40) | (u64)(u32)(ew[e] * 16777216.0f);
        u64 old = atomicAdd(&packed[b * NN + dst], contrib);
        rank[(size_t)b * EE + e] = (u16)(old >> 40);
        return;
    }

    // ---- gemm: 1 of every 5 blocks; q in [0, NGEMM) exactly ----
    int b = q / GB;
    int row_base = (q - b * GB) * 64;
    const float* x = (b == 0) ? x1 : (b == 1) ? x2 : x3;
    const float* W = (b == 0) ? W1 : (b == 1) ? W2 : W3;
    __half* hb = h + (size_t)b * NN * HID;

    int t  = threadIdx.x;
    int tx = t & 15;
    int ty = t >> 4;

    float acc[4][4] = {};
    const float4* x4 = reinterpret_cast<const float4*>(x);
    const float4* W4 = reinterpret_cast<const float4*>(W);
    for (int kt = 0; kt < INF_ / 32; ++kt) {
#pragma unroll
        for (int j = 0; j < 2; ++j) {               // stage x: 512 float4
            int flat = t + j * 256;
            int rr = flat >> 3, c4 = flat & 7;
            int gr = row_base + rr;
            float4 v = (gr < NN)
                ? x4[(size_t)gr * (INF_ / 4) + kt * 8 + c4]
                : make_float4(0.f, 0.f, 0.f, 0.f);
            *reinterpret_cast<float4*>(&xs[rr][c4 * 4]) = v;
        }
#pragma unroll
        for (int j = 0; j < 2; ++j) {               // stage W: 512 float4
            int flat = t + j * 256;
            int rr = flat >> 4, c4 = flat & 15;
            *reinterpret_cast<float4*>(&Ws[rr][c4 * 4]) = W4[(kt * 32 + rr) * 16 + c4];
        }
        __syncthreads();
#pragma unroll
        for (int k = 0; k < 32; ++k) {
            float4 wv = *reinterpret_cast<const float4*>(&Ws[k][tx * 4]);
            float xv[4];
#pragma unroll
            for (int i = 0; i < 4; ++i) xv[i] = xs[ty * 4 + i][k];
#pragma unroll
            for (int i = 0; i < 4; ++i) {
                acc[i][0] = fmaf(xv[i], wv.x, acc[i][0]);
                acc[i][1] = fmaf(xv[i], wv.y, acc[i][1]);
                acc[i][2] = fmaf(xv[i], wv.z, acc[i][2]);
                acc[i][3] = fmaf(xv[i], wv.w, acc[i][3]);
            }
        }
        __syncthreads();
    }
#pragma unroll
    for (int i = 0; i < 4; ++i) {
        int row = row_base + ty * 4 + i;
        if (row < NN) {
            ushort4 v;
            v.x = __half_as_ushort(__float2half(acc[i][0]));
            v.y = __half_as_ushort(__float2half(acc[i][1]));
            v.z = __half_as_ushort(__float2half(acc[i][2]));
            v.w = __half_as_ushort(__float2half(acc[i][3]));
            *reinterpret_cast<ushort4*>(&hb[(size_t)row * HID + tx * 4]) = v;
        }
    }
}

// ---------------- offsets: unpack packed -> cnt/dinv, block scan -> start ----------------
__global__ __launch_bounds__(256) void k_offsets(const u64* __restrict__ packed,
                                                 int* __restrict__ cnt, float* __restrict__ dinv,
                                                 int* __restrict__ start, int* __restrict__ total) {
    __shared__ int s[256];
    __shared__ int s_base;
    int t = threadIdx.x;
    int base_i = blockIdx.x * 1024 + t * 4;
    int c[4]; int sum = 0;
#pragma unroll
    for (int k = 0; k < 4; ++k) {
        int i = base_i + k;
        if (i < TOTN) {
            u64 p = packed[i];
            c[k] = (int)(p >> 40);
            cnt[i] = c[k];
            dinv[i] = rsqrtf(1.0f + (float)(p & MASK40) * (1.0f / 16777216.0f));
        } else c[k] = 0;
        sum += c[k];
    }
    s[t] = sum;
    __syncthreads();
    for (int d = 1; d < 256; d <<= 1) {
        int v = (t >= d) ? s[t - d] : 0;
        __syncthreads();
        s[t] += v;
        __syncthreads();
    }
    if (t == 255) s_base = atomicAdd(total, s[255]);
    __syncthreads();
    int run = s_base + s[t] - sum;
#pragma unroll
    for (int k = 0; k < 4; ++k) {
        int i = base_i + k;
        if (i < TOTN) start[i] = run;
        run += c[k];
    }
}

// ---------------- fill CSR (atomic-free): csr[start+rank] = fp16(dinv_src*w)<<16 | src ----------------
__global__ __launch_bounds__(256) void k_fill(
        const int* __restrict__ ei1, const int* __restrict__ ei2, const int* __restrict__ ei3,
        const float* __restrict__ ew1, const float* __restrict__ ew2, const float* __restrict__ ew3,
        const float* __restrict__ dinv, const int* __restrict__ start,
        const u16* __restrict__ rank, u32* __restrict__ csr) {
    int b = blockIdx.y;
    const int*   ei = (b == 0) ? ei1 : (b == 1) ? ei2 : ei3;
    const float* ew = (b == 0) ? ew1 : (b == 1) ? ew2 : ew3;
    int e = blockIdx.x * 256 + threadIdx.x;
    int src = ei[e];
    int dst = ei[EE + e];
    float normp = dinv[b * NN + src] * ew[e];        // dinv[dst] applied at aggregation
    int pos = start[b * NN + dst] + (int)rank[(size_t)b * EE + e];
    csr[pos] = ((u32)__half_as_ushort(__float2half(normp)) << 16) | (u32)src;
}

// ---------------- fused: layer-1 agg (3 branches, MLP-8) + attention + layer-2 GEMM ----------------
__global__ __launch_bounds__(256) void k_agg_attn(
        const u32* __restrict__ csr, const int* __restrict__ start, const int* __restrict__ cnt,
        const float* __restrict__ dinv,
        const float* __restrict__ b1, const float* __restrict__ b2, const float* __restrict__ b3,
        const __half* __restrict__ h,
        const float* __restrict__ fc_w, const float* __restrict__ fc_b,
        const float* __restrict__ W11, const float* __restrict__ W22, const float* __restrict__ W33,
        __half* __restrict__ h2, float* __restrict__ coef_out) {
    __shared__ float Wls[3][HID][OUTF];   // 24 KB
    __shared__ float cls[4][HID];         // 1 KB
    int t = threadIdx.x;

    {   // stage layer-2 weights
        const float4* w40 = reinterpret_cast<const float4*>(W11);
        const float4* w41 = reinterpret_cast<const float4*>(W22);
        const float4* w42 = reinterpret_cast<const float4*>(W33);
        float4* d0 = reinterpret_cast<float4*>(&Wls[0][0][0]);
        float4* d1 = reinterpret_cast<float4*>(&Wls[1][0][0]);
        float4* d2 = reinterpret_cast<float4*>(&Wls[2][0][0]);
#pragma unroll
        for (int j = 0; j < 2; ++j) {
            d0[t + j * 256] = w40[t + j * 256];
            d1[t + j * 256] = w41[t + j * 256];
            d2[t + j * 256] = w42[t + j * 256];
        }
    }

    int f   = t & 63;
    int sub = __builtin_amdgcn_readfirstlane(t >> 6);
    int n   = blockIdx.x * 4 + sub;                  // 50000 = 12500*4 exact
    float wv = fc_w[f];
    float fb = fc_b[0];

    float ev[3], c[3];
#pragma unroll
    for (int b = 0; b < 3; ++b) {
        const float* bi = (b == 0) ? b1 : (b == 1) ? b2 : b3;
        const __half* hb = h + (size_t)b * NN * HID;
        int i  = b * NN + n;
        int cc = cnt[i];
        int st = start[i];
        float d = dinv[i];
        float hs = __half2float(hb[(size_t)n * HID + f]);

        float ssum = 0.f;
        int j = 0;
        for (; j + 8 <= cc; j += 8) {                // 8 gathers in flight per wave
            u32 ee[8]; float vv[8];
#pragma unroll
            for (int u = 0; u < 8; ++u) ee[u] = csr[st + j + u];
#pragma unroll
            for (int u = 0; u < 8; ++u)
                vv[u] = __half2float(hb[(size_t)(ee[u] & 0xffff) * HID + f]);
#pragma unroll
            for (int u = 0; u < 8; ++u)
                ssum = fmaf(__half2float(__ushort_as_half((u16)(ee[u] >> 16))), vv[u], ssum);
        }
        for (; j < cc; ++j) {
            u32 e0 = csr[st + j];
            ssum = fmaf(__half2float(__ushort_as_half((u16)(e0 >> 16))),
                        __half2float(hb[(size_t)(e0 & 0xffff) * HID + f]), ssum);
        }
        float acc = bi[f] + d * d * hs + d * ssum;
        ev[b] = fmaxf(acc, 0.f);                     // ReLU

        float dd = ev[b] * wv;
#pragma unroll
        for (int off = 32; off > 0; off >>= 1) dd += __shfl_xor(dd, off);
        float z = dd + fb;
        z = (z > 0.f) ? z : 0.01f * z;
        c[b] = expf(z);
    }
    float cd = c[0] + c[1] + c[2];
    float coef0 = c[0] / cd, coef1 = c[1] / cd, coef2 = c[2] / cd;
    cls[sub][f] = ev[0] * coef0 + ev[1] * coef1 + ev[2] * coef2;
    if (f == 0) {
        coef_out[n]          = coef0;
        coef_out[NN + n]     = coef1;
        coef_out[2 * NN + n] = coef2;
    }
    __syncthreads();

    // ---- layer-2 GEMM for this block's 4 nodes ----
    for (int idx = t; idx < 384; idx += 256) {
        int node = idx / 96;
        int rem  = idx - node * 96;
        int br   = rem >> 5;
        int col  = rem & 31;
        float a = 0.f;
#pragma unroll
        for (int k = 0; k < HID; ++k)
            a = fmaf(cls[node][k], Wls[br][k][col], a);
        h2[(size_t)br * NN * OUTF + (size_t)(blockIdx.x * 4 + node) * OUTF + col] = __float2half(a);
    }
}

// ---------------- layer-2 aggregation: one wave per node, MLP-8 per wave ----------------
__global__ __launch_bounds__(256) void k_agg2(
        const u32* __restrict__ csr, const int* __restrict__ start, const int* __restrict__ cnt,
        const float* __restrict__ dinv,
        const float* __restrict__ b11, const float* __restrict__ b22, const float* __restrict__ b33,
        const __half* __restrict__ h2, float* __restrict__ out) {
    int f    = threadIdx.x & 31;
    int half = (threadIdx.x >> 5) & 1;
    int sub  = __builtin_amdgcn_readfirstlane(threadIdx.x >> 6);
    int n    = blockIdx.x * 4 + sub;

    float tot = b11[f] + b22[f] + b33[f];
#pragma unroll
    for (int b = 0; b < 3; ++b) {
        int i  = b * NN + n;
        int cc = cnt[i];
        int st = start[i];
        const __half* h2b = h2 + (size_t)b * NN * OUTF;
        float accb = 0.f;
        int j = half;
        for (; j + 6 < cc; j += 8) {                 // 4 gathers in flight per half-wave
            u32 ee[4]; float vv[4];
#pragma unroll
            for (int u = 0; u < 4; ++u) ee[u] = csr[st + j + 2 * u];
#pragma unroll
            for (int u = 0; u < 4; ++u)
                vv[u] = __half2float(h2b[(size_t)(ee[u] & 0xffff) * OUTF + f]);
#pragma unroll
            for (int u = 0; u < 4; ++u)
                accb = fmaf(__half2float(__ushort_as_half((u16)(ee[u] >> 16))), vv[u], accb);
        }
        for (; j < cc; j += 2) {
            u32 e0 = csr[st + j];
            accb = fmaf(__half2float(__ushort_as_half((u16)(e0 >> 16))),
                        __half2float(h2b[(size_t)(e0 & 0xffff) * OUTF + f]), accb);
        }
        accb += __shfl_xor(accb, 32);
        float d = dinv[i];
        tot += d * accb + d * d * __half2float(h2b[(size_t)n * OUTF + f]);
    }
    if (half == 0) out[(size_t)n * OUTF + f] = tot;
}

// ---------------- launch ----------------
extern "C" void kernel_launch(void* const* d_in, const int* in_sizes, int n_in,
                              void* d_out, int out_size, void* d_ws, size_t ws_size,
                              hipStream_t stream) {
    const float* x1  = (const float*)d_in[0];
    const float* x2  = (const float*)d_in[1];
    const float* x3  = (const float*)d_in[2];
    const int*   ei1 = (const int*)d_in[3];
    const int*   ei2 = (const int*)d_in[4];
    const int*   ei3 = (const int*)d_in[5];
    const float* ew1 = (const float*)d_in[6];
    const float* ew2 = (const float*)d_in[7];
    const float* ew3 = (const float*)d_in[8];
    const float* W1  = (const float*)d_in[9];
    const float* W2  = (const float*)d_in[10];
    const float* W3  = (const float*)d_in[11];
    const float* b1  = (const float*)d_in[12];
    const float* b2  = (const float*)d_in[13];
    const float* b3  = (const float*)d_in[14];
    const float* fcw = (const float*)d_in[15];
    const float* fcb = (const float*)d_in[16];
    const float* W11 = (const float*)d_in[17];
    const float* W22 = (const float*)d_in[18];
    const float* W33 = (const float*)d_in[19];
    const float* b11 = (const float*)d_in[20];
    const float* b22 = (const float*)d_in[21];
    const float* b33 = (const float*)d_in[22];

    float* out = (float*)d_out;
    float* coef_out = out + (size_t)NN * OUTF;

    u64*   packed = (u64*)d_ws;                            // 3N u64
    u32*   csr    = (u32*)(packed + TOTN);                 // 3E u32
    u16*   rank   = (u16*)(csr + 3 * EE);                  // 3E u16
    float* dinv   = (float*)(rank + 3 * EE);               // 3N
    int*   cnt    = (int*)(dinv + TOTN);                   // 3N
    int*   start  = cnt + TOTN;                            // 3N
    int*   total  = start + TOTN;                          // 64 pad
    __half* h     = (__half*)(total + 64);                 // 3N*64 fp16
    __half* h2    = h + (size_t)TOTN * HID;                // 3N*32 fp16

    k_init<<<dim3((TOTN + 255) / 256), 256, 0, stream>>>(packed, total);
    k_histgemm<<<dim3(NGEMM * 5), 256, 0, stream>>>(ei1, ei2, ei3, ew1, ew2, ew3,
                                                    packed, rank,
                                                    x1, x2, x3, W1, W2, W3, h);
    k_offsets<<<dim3((TOTN + 1023) / 1024), 256, 0, stream>>>(packed, cnt, dinv, start, total);
    k_fill<<<dim3(EE / 256, 3), 256, 0, stream>>>(ei1, ei2, ei3, ew1, ew2, ew3,
                                                  dinv, start, rank, csr);

    k_agg_attn<<<dim3(NN / 4), 256, 0, stream>>>(csr, start, cnt, dinv, b1, b2, b3,
                                                 h, fcw, fcb, W11, W22, W33, h2, coef_out);
    k_agg2<<<dim3(NN / 4), 256, 0, stream>>>(csr, start, cnt, dinv,
                                             b11, b22, b33, h2, out);
}

// Round 8
// 345.336 us; speedup vs baseline: 1.2962x; 1.0299x over previous
//
#include <hip/hip_runtime.h>
#include <hip/hip_fp16.h>
#include <math.h>

#define NN    50000
#define INF_  256
#define HID   64
#define OUTF  32
#define EE    800000
#define TOTN  (3 * NN)
#define NBKT  196            // buckets per branch (256 nodes each; last has 80)
#define NBIN  (3 * NBKT)     // 588
#define CBLK  196            // count/scatter blocks per branch (4096 edges each)
#define NCNT  (3 * CBLK)     // 588
#define GB    782            // gemm tiles per branch
#define NGEMM (3 * GB)       // 2346
#define MAXB  5120           // max edges per bucket (mean 4082, sigma 64)

typedef unsigned long long u64;
typedef unsigned int       u32;
typedef unsigned short     u16;

// ---------------- init: zero bucket totals ----------------
__global__ __launch_bounds__(256) void k_init(u32* __restrict__ bin_total) {
    int i = blockIdx.x * 256 + threadIdx.x;
    if (i < NBIN) bin_total[i] = 0;
}

// ---------------- fused: bucket-count (LDS hist) + layer-1 GEMM, 4:1 interleave ----------------
__global__ __launch_bounds__(256) void k_cntgemm(
        const int* __restrict__ ei1, const int* __restrict__ ei2, const int* __restrict__ ei3,
        u32* __restrict__ bin_total, u32* __restrict__ blockbase,
        const float* __restrict__ x1, const float* __restrict__ x2, const float* __restrict__ x3,
        const float* __restrict__ W1, const float* __restrict__ W2, const float* __restrict__ W3,
        __half* __restrict__ h) {
    __shared__ float xs[64][36];    // 9.2 KB
    __shared__ float Ws[32][68];    // 8.7 KB
    __shared__ u32 bins[NBKT];      // 0.8 KB
    int bid = blockIdx.x;
    int q = bid / 5, r = bid - q * 5;
    int t = threadIdx.x;

    if (r == 4) {                   // ---- count block: q in [0,588) ----
        int cb  = q;
        int br  = cb / CBLK;
        int blk = cb - br * CBLK;
        const int* ei = (br == 0) ? ei1 : (br == 1) ? ei2 : ei3;
        for (int i = t; i < NBKT; i += 256) bins[i] = 0;
        __syncthreads();
        int e0 = blk * 4096;
#pragma unroll
        for (int k = 0; k < 16; ++k) {
            int e = e0 + k * 256 + t;
            if (e < EE) atomicAdd(&bins[(u32)ei[EE + e] >> 8], 1u);
        }
        __syncthreads();
        for (int i = t; i < NBKT; i += 256) {
            u32 c = bins[i];
            u32 base = atomicAdd(&bin_total[br * NBKT + i], c);
            blockbase[cb * NBKT + i] = base;
        }
        return;
    }

    // ---- gemm: gid in [0, NGEMM) ----
    int gid = q * 4 + r;
    if (gid >= NGEMM) return;
    int b = gid / GB;
    int row_base = (gid - b * GB) * 64;
    const float* x = (b == 0) ? x1 : (b == 1) ? x2 : x3;
    const float* W = (b == 0) ? W1 : (b == 1) ? W2 : W3;
    __half* hb = h + (size_t)b * NN * HID;

    int tx = t & 15;
    int ty = t >> 4;
    float acc[4][4] = {};
    const float4* x4 = reinterpret_cast<const float4*>(x);
    const float4* W4 = reinterpret_cast<const float4*>(W);
    for (int kt = 0; kt < INF_ / 32; ++kt) {
#pragma unroll
        for (int j = 0; j < 2; ++j) {
            int flat = t + j * 256;
            int rr = flat >> 3, c4 = flat & 7;
            int gr = row_base + rr;
            float4 v = (gr < NN)
                ? x4[(size_t)gr * (INF_ / 4) + kt * 8 + c4]
                : make_float4(0.f, 0.f, 0.f, 0.f);
            *reinterpret_cast<float4*>(&xs[rr][c4 * 4]) = v;
        }
#pragma unroll
        for (int j = 0; j < 2; ++j) {
            int flat = t + j * 256;
            int rr = flat >> 4, c4 = flat & 15;
            *reinterpret_cast<float4*>(&Ws[rr][c4 * 4]) = W4[(kt * 32 + rr) * 16 + c4];
        }
        __syncthreads();
#pragma unroll
        for (int k = 0; k < 32; ++k) {
            float4 wv = *reinterpret_cast<const float4*>(&Ws[k][tx * 4]);
            float xv[4];
#pragma unroll
            for (int i = 0; i < 4; ++i) xv[i] = xs[ty * 4 + i][k];
#pragma unroll
            for (int i = 0; i < 4; ++i) {
                acc[i][0] = fmaf(xv[i], wv.x, acc[i][0]);
                acc[i][1] = fmaf(xv[i], wv.y, acc[i][1]);
                acc[i][2] = fmaf(xv[i], wv.z, acc[i][2]);
                acc[i][3] = fmaf(xv[i], wv.w, acc[i][3]);
            }
        }
        __syncthreads();
    }
#pragma unroll
    for (int i = 0; i < 4; ++i) {
        int row = row_base + ty * 4 + i;
        if (row < NN) {
            ushort4 v;
            v.x = __half_as_ushort(__float2half(acc[i][0]));
            v.y = __half_as_ushort(__float2half(acc[i][1]));
            v.z = __half_as_ushort(__float2half(acc[i][2]));
            v.w = __half_as_ushort(__float2half(acc[i][3]));
            *reinterpret_cast<ushort4*>(&hb[(size_t)row * HID + tx * 4]) = v;
        }
    }
}

// ---------------- scan 588 bucket totals ----------------
__global__ __launch_bounds__(256) void k_scan(const u32* __restrict__ bin_total,
                                              u32* __restrict__ binstart) {
    if (threadIdx.x == 0) {
        u32 run = 0;
        for (int i = 0; i < NBIN; ++i) { binstart[i] = run; run += bin_total[i]; }
        binstart[NBIN] = run;
    }
}

// ---------------- scatter edges into bucket-contiguous regions ----------------
__global__ __launch_bounds__(256) void k_scatter(
        const int* __restrict__ ei1, const int* __restrict__ ei2, const int* __restrict__ ei3,
        const float* __restrict__ ew1, const float* __restrict__ ew2, const float* __restrict__ ew3,
        const u32* __restrict__ binstart, const u32* __restrict__ blockbase,
        u64* __restrict__ bucketed) {
    __shared__ u32 cur[NBKT];
    int cb  = blockIdx.x;            // 0..587
    int br  = cb / CBLK;
    int blk = cb - br * CBLK;
    const int*   ei = (br == 0) ? ei1 : (br == 1) ? ei2 : ei3;
    const float* ew = (br == 0) ? ew1 : (br == 1) ? ew2 : ew3;
    int t = threadIdx.x;
    for (int i = t; i < NBKT; i += 256) cur[i] = 0;
    __syncthreads();
    int e0 = blk * 4096;
#pragma unroll
    for (int k = 0; k < 16; ++k) {
        int e = e0 + k * 256 + t;
        if (e < EE) {
            u32 dst = (u32)ei[EE + e];
            u32 src = (u32)ei[e];
            u32 bkt = dst >> 8;
            u32 rnk = atomicAdd(&cur[bkt], 1u);
            u32 pos = binstart[br * NBKT + bkt] + blockbase[cb * NBKT + bkt] + rnk;
            bucketed[pos] = ((u64)__float_as_uint(ew[e]) << 32) | (src << 8) | (dst & 0xffu);
        }
    }
}

// ---------------- per-bucket CSR build, all in LDS ----------------
__global__ __launch_bounds__(256) void k_bucket(
        const u64* __restrict__ bucketed, const u32* __restrict__ bin_total,
        const u32* __restrict__ binstart,
        int* __restrict__ cnt, int* __restrict__ start, float* __restrict__ dinv,
        u32* __restrict__ csr) {
    __shared__ u32   scnt[256];
    __shared__ float swsum[256];
    __shared__ u32   scur[256];
    __shared__ u32   sscan[256];
    __shared__ u32   lcsr[MAXB];   // 20.5 KB
    int bin = blockIdx.x;          // 0..587, branch-major
    int br  = bin / NBKT;
    int bkt = bin - br * NBKT;
    int t = threadIdx.x;
    u32 base = binstart[bin];
    u32 ecnt = bin_total[bin];
    scnt[t] = 0; swsum[t] = 0.f; scur[t] = 0;
    __syncthreads();
    for (u32 i = t; i < ecnt; i += 256) {
        u64 e = bucketed[base + i];
        u32 dl = (u32)e & 0xffu;
        atomicAdd(&scnt[dl], 1u);
        atomicAdd(&swsum[dl], __uint_as_float((u32)(e >> 32)));
    }
    __syncthreads();
    sscan[t] = scnt[t];
    __syncthreads();
    for (int d = 1; d < 256; d <<= 1) {
        u32 v = (t >= d) ? sscan[t - d] : 0;
        __syncthreads();
        sscan[t] += v;
        __syncthreads();
    }
    u32 lstart = sscan[t] - scnt[t];
    int n = bkt * 256 + t;
    if (n < NN) {
        int gi = br * NN + n;
        cnt[gi]   = (int)scnt[t];
        start[gi] = (int)(base + lstart);
        dinv[gi]  = rsqrtf(1.0f + swsum[t]);
    }
    __syncthreads();
    for (u32 i = t; i < ecnt; i += 256) {
        u64 e = bucketed[base + i];
        u32 dl  = (u32)e & 0xffu;
        u32 src = (u32)(e >> 8) & 0xffffu;
        float w = __uint_as_float((u32)(e >> 32));
        u32 rnk = atomicAdd(&scur[dl], 1u);
        u32 ls  = sscan[dl] - scnt[dl];
        lcsr[ls + rnk] = ((u32)__half_as_ushort(__float2half(w)) << 16) | src;
    }
    __syncthreads();
    for (u32 i = t; i < ecnt; i += 256) csr[base + i] = lcsr[i];
}

// ---------------- rescale csr weights by dinv[src] (coalesced + L2-hot gather) ----------------
__global__ __launch_bounds__(256) void k_rescale(u32* __restrict__ csr,
                                                 const float* __restrict__ dinv) {
    int i = blockIdx.x * 256 + threadIdx.x;      // grid covers 3E exactly
    int br = i / EE;
    u32 e = csr[i];
    u32 src = e & 0xffffu;
    float w = __half2float(__ushort_as_half((u16)(e >> 16)));
    float nw = w * dinv[br * NN + src];
    csr[i] = ((u32)__half_as_ushort(__float2half(nw)) << 16) | src;
}

// ---------------- fused: layer-1 agg (3 branches, MLP-8) + attention + layer-2 GEMM ----------------
__global__ __launch_bounds__(256) void k_agg_attn(
        const u32* __restrict__ csr, const int* __restrict__ start, const int* __restrict__ cnt,
        const float* __restrict__ dinv,
        const float* __restrict__ b1, const float* __restrict__ b2, const float* __restrict__ b3,
        const __half* __restrict__ h,
        const float* __restrict__ fc_w, const float* __restrict__ fc_b,
        const float* __restrict__ W11, const float* __restrict__ W22, const float* __restrict__ W33,
        __half* __restrict__ h2, float* __restrict__ coef_out) {
    __shared__ float Wls[3][HID][OUTF];   // 24 KB
    __shared__ float cls[4][HID];         // 1 KB
    int t = threadIdx.x;

    {   // stage layer-2 weights
        const float4* w40 = reinterpret_cast<const float4*>(W11);
        const float4* w41 = reinterpret_cast<const float4*>(W22);
        const float4* w42 = reinterpret_cast<const float4*>(W33);
        float4* d0 = reinterpret_cast<float4*>(&Wls[0][0][0]);
        float4* d1 = reinterpret_cast<float4*>(&Wls[1][0][0]);
        float4* d2 = reinterpret_cast<float4*>(&Wls[2][0][0]);
#pragma unroll
        for (int j = 0; j < 2; ++j) {
            d0[t + j * 256] = w40[t + j * 256];
            d1[t + j * 256] = w41[t + j * 256];
            d2[t + j * 256] = w42[t + j * 256];
        }
    }

    int f   = t & 63;
    int sub = __builtin_amdgcn_readfirstlane(t >> 6);
    int n   = blockIdx.x * 4 + sub;                  // 50000 = 12500*4 exact
    float wv = fc_w[f];
    float fb = fc_b[0];

    float ev[3], c[3];
#pragma unroll
    for (int b = 0; b < 3; ++b) {
        const float* bi = (b == 0) ? b1 : (b == 1) ? b2 : b3;
        const __half* hb = h + (size_t)b * NN * HID;
        int i  = b * NN + n;
        int cc = cnt[i];
        int st = start[i];
        float d = dinv[i];
        float hs = __half2float(hb[(size_t)n * HID + f]);

        float ssum = 0.f;
        int j = 0;
        for (; j + 8 <= cc; j += 8) {
            u32 ee[8]; float vv[8];
#pragma unroll
            for (int u = 0; u < 8; ++u) ee[u] = csr[st + j + u];
#pragma unroll
            for (int u = 0; u < 8; ++u)
                vv[u] = __half2float(hb[(size_t)(ee[u] & 0xffff) * HID + f]);
#pragma unroll
            for (int u = 0; u < 8; ++u)
                ssum = fmaf(__half2float(__ushort_as_half((u16)(ee[u] >> 16))), vv[u], ssum);
        }
        for (; j < cc; ++j) {
            u32 e0 = csr[st + j];
            ssum = fmaf(__half2float(__ushort_as_half((u16)(e0 >> 16))),
                        __half2float(hb[(size_t)(e0 & 0xffff) * HID + f]), ssum);
        }
        float acc = bi[f] + d * d * hs + d * ssum;
        ev[b] = fmaxf(acc, 0.f);                     // ReLU

        float dd = ev[b] * wv;
#pragma unroll
        for (int off = 32; off > 0; off >>= 1) dd += __shfl_xor(dd, off);
        float z = dd + fb;
        z = (z > 0.f) ? z : 0.01f * z;
        c[b] = expf(z);
    }
    float cd = c[0] + c[1] + c[2];
    float coef0 = c[0] / cd, coef1 = c[1] / cd, coef2 = c[2] / cd;
    cls[sub][f] = ev[0] * coef0 + ev[1] * coef1 + ev[2] * coef2;
    if (f == 0) {
        coef_out[n]          = coef0;
        coef_out[NN + n]     = coef1;
        coef_out[2 * NN + n] = coef2;
    }
    __syncthreads();

    for (int idx = t; idx < 384; idx += 256) {
        int node = idx / 96;
        int rem  = idx - node * 96;
        int brc  = rem >> 5;
        int col  = rem & 31;
        float a = 0.f;
#pragma unroll
        for (int k = 0; k < HID; ++k)
            a = fmaf(cls[node][k], Wls[brc][k][col], a);
        h2[(size_t)brc * NN * OUTF + (size_t)(blockIdx.x * 4 + node) * OUTF + col] = __float2half(a);
    }
}

// ---------------- layer-2 aggregation: one wave per node, MLP-4 per half-wave ----------------
__global__ __launch_bounds__(256) void k_agg2(
        const u32* __restrict__ csr, const int* __restrict__ start, const int* __restrict__ cnt,
        const float* __restrict__ dinv,
        const float* __restrict__ b11, const float* __restrict__ b22, const float* __restrict__ b33,
        const __half* __restrict__ h2, float* __restrict__ out) {
    int f    = threadIdx.x & 31;
    int half = (threadIdx.x >> 5) & 1;
    int sub  = __builtin_amdgcn_readfirstlane(threadIdx.x >> 6);
    int n    = blockIdx.x * 4 + sub;

    float tot = b11[f] + b22[f] + b33[f];
#pragma unroll
    for (int b = 0; b < 3; ++b) {
        int i  = b * NN + n;
        int cc = cnt[i];
        int st = start[i];
        const __half* h2b = h2 + (size_t)b * NN * OUTF;
        float accb = 0.f;
        int j = half;
        for (; j + 6 < cc; j += 8) {
            u32 ee[4]; float vv[4];
#pragma unroll
            for (int u = 0; u < 4; ++u) ee[u] = csr[st + j + 2 * u];
#pragma unroll
            for (int u = 0; u < 4; ++u)
                vv[u] = __half2float(h2b[(size_t)(ee[u] & 0xffff) * OUTF + f]);
#pragma unroll
            for (int u = 0; u < 4; ++u)
                accb = fmaf(__half2float(__ushort_as_half((u16)(ee[u] >> 16))), vv[u], accb);
        }
        for (; j < cc; j += 2) {
            u32 e0 = csr[st + j];
            accb = fmaf(__half2float(__ushort_as_half((u16)(e0 >> 16))),
                        __half2float(h2b[(size_t)(e0 & 0xffff) * OUTF + f]), accb);
        }
        accb += __shfl_xor(accb, 32);
        float d = dinv[i];
        tot += d * accb + d * d * __half2float(h2b[(size_t)n * OUTF + f]);
    }
    if (half == 0) out[(size_t)n * OUTF + f] = tot;
}

// ---------------- launch ----------------
extern "C" void kernel_launch(void* const* d_in, const int* in_sizes, int n_in,
                              void* d_out, int out_size, void* d_ws, size_t ws_size,
                              hipStream_t stream) {
    const float* x1  = (const float*)d_in[0];
    const float* x2  = (const float*)d_in[1];
    const float* x3  = (const float*)d_in[2];
    const int*   ei1 = (const int*)d_in[3];
    const int*   ei2 = (const int*)d_in[4];
    const int*   ei3 = (const int*)d_in[5];
    const float* ew1 = (const float*)d_in[6];
    const float* ew2 = (const float*)d_in[7];
    const float* ew3 = (const float*)d_in[8];
    const float* W1  = (const float*)d_in[9];
    const float* W2  = (const float*)d_in[10];
    const float* W3  = (const float*)d_in[11];
    const float* b1  = (const float*)d_in[12];
    const float* b2  = (const float*)d_in[13];
    const float* b3  = (const float*)d_in[14];
    const float* fcw = (const float*)d_in[15];
    const float* fcb = (const float*)d_in[16];
    const float* W11 = (const float*)d_in[17];
    const float* W22 = (const float*)d_in[18];
    const float* W33 = (const float*)d_in[19];
    const float* b11 = (const float*)d_in[20];
    const float* b22 = (const float*)d_in[21];
    const float* b33 = (const float*)d_in[22];

    float* out = (float*)d_out;
    float* coef_out = out + (size_t)NN * OUTF;

    // workspace layout
    u64*   bucketed  = (u64*)d_ws;                           // 3E u64   19.2 MB
    u32*   csr       = (u32*)(bucketed + 3 * EE);            // 3E u32    9.6 MB
    u32*   bin_total = csr + 3 * EE;                         // 588
    u32*   binstart  = bin_total + NBIN;                     // 589 (+pad)
    u32*   blockbase = binstart + NBIN + 4;                  // 588*196   461 KB
    float* dinv      = (float*)(blockbase + NCNT * NBKT);    // 3N
    int*   cnt       = (int*)(dinv + TOTN);                  // 3N
    int*   start     = cnt + TOTN;                           // 3N
    __half* h        = (__half*)(start + TOTN);              // 3N*64    19.2 MB
    __half* h2       = h + (size_t)TOTN * HID;               // 3N*32     9.6 MB

    k_init<<<dim3(3), 256, 0, stream>>>(bin_total);
    k_cntgemm<<<dim3(NCNT * 5), 256, 0, stream>>>(ei1, ei2, ei3, bin_total, blockbase,
                                                  x1, x2, x3, W1, W2, W3, h);
    k_scan<<<dim3(1), 256, 0, stream>>>(bin_total, binstart);
    k_scatter<<<dim3(NCNT), 256, 0, stream>>>(ei1, ei2, ei3, ew1, ew2, ew3,
                                              binstart, blockbase, bucketed);
    k_bucket<<<dim3(NBIN), 256, 0, stream>>>(bucketed, bin_total, binstart,
                                             cnt, start, dinv, csr);
    k_rescale<<<dim3(3 * EE / 256), 256, 0, stream>>>(csr, dinv);

    k_agg_attn<<<dim3(NN / 4), 256, 0, stream>>>(csr, start, cnt, dinv, b1, b2, b3,
                                                 h, fcw, fcb, W11, W22, W33, h2, coef_out);
    k_agg2<<<dim3(NN / 4), 256, 0, stream>>>(csr, start, cnt, dinv,
                                             b11, b22, b33, h2, out);
}

// Round 9
// 337.687 us; speedup vs baseline: 1.3256x; 1.0227x over previous
//
#include <hip/hip_runtime.h>
#include <hip/hip_fp16.h>
#include <math.h>

#define NN    50000
#define INF_  256
#define HID   64
#define OUTF  32
#define EE    800000
#define TOTN  (3 * NN)
#define NBKT  196
#define NBIN  (3 * NBKT)     // 588
#define CBLK  196
#define NCNT  (3 * CBLK)     // 588
#define GB    782            // gemm tiles per branch (64 rows)
#define NGEMM (3 * GB)       // 2346
#define MAXB  5120

typedef unsigned long long u64;
typedef unsigned int       u32;
typedef unsigned short     u16;
typedef _Float16           f16;
typedef f16   f16x8 __attribute__((ext_vector_type(8)));
typedef f16   f16x4 __attribute__((ext_vector_type(4)));
typedef float f32x4 __attribute__((ext_vector_type(4)));

// ---------------- prep: zero bin totals + transpose/convert W -> Wt fp16 [col][k] ----------------
__global__ __launch_bounds__(256) void k_prep(
        const float* __restrict__ W1, const float* __restrict__ W2, const float* __restrict__ W3,
        f16* __restrict__ Wt, u32* __restrict__ bin_total) {
    int blk = blockIdx.x, t = threadIdx.x;
    if (blk == 3) {
        for (int i = t; i < NBIN; i += 256) bin_total[i] = 0;
        return;
    }
    const float* W = (blk == 0) ? W1 : (blk == 1) ? W2 : W3;
    f16* wt = Wt + blk * HID * INF_;
    for (int idx = t; idx < INF_ * HID; idx += 256) {
        int k = idx >> 6, c = idx & 63;
        wt[c * INF_ + k] = (f16)W[idx];
    }
}

// ---------------- fused: bucket-count + MFMA fp16 layer-1 GEMM, 4:1 interleave ----------------
__global__ __launch_bounds__(256) void k_cntgemm(
        const int* __restrict__ ei1, const int* __restrict__ ei2, const int* __restrict__ ei3,
        u32* __restrict__ bin_total, u32* __restrict__ blockbase,
        const float* __restrict__ x1, const float* __restrict__ x2, const float* __restrict__ x3,
        const f16* __restrict__ Wt, __half* __restrict__ h) {
    __shared__ f16 xl[64][72];   // 9.2 KB (pad 8 f16 = 16 B)
    __shared__ f16 wl[64][72];   // 9.2 KB
    int bid = blockIdx.x;
    int q = bid / 5, r = bid - q * 5;
    int t = threadIdx.x;

    if (r == 4) {                   // ---- count block: q in [0,588) ----
        u32* bins = (u32*)xl;
        int cb  = q;
        int br  = cb / CBLK;
        int blk = cb - br * CBLK;
        const int* ei = (br == 0) ? ei1 : (br == 1) ? ei2 : ei3;
        for (int i = t; i < NBKT; i += 256) bins[i] = 0;
        __syncthreads();
        int e0 = blk * 4096;
#pragma unroll
        for (int k = 0; k < 16; ++k) {
            int e = e0 + k * 256 + t;
            if (e < EE) atomicAdd(&bins[(u32)ei[EE + e] >> 8], 1u);
        }
        __syncthreads();
        for (int i = t; i < NBKT; i += 256) {
            u32 c = bins[i];
            u32 base = atomicAdd(&bin_total[br * NBKT + i], c);
            blockbase[cb * NBKT + i] = base;
        }
        return;
    }

    // ---- gemm: gid in [0, NGEMM) ----
    int gid = q * 4 + r;
    if (gid >= NGEMM) return;
    int b = gid / GB;
    int row_base = (gid - b * GB) * 64;
    const float4* x4 = reinterpret_cast<const float4*>((b == 0) ? x1 : (b == 1) ? x2 : x3);
    const f16* wt = Wt + b * HID * INF_;
    __half* hb = h + (size_t)b * NN * HID;

    int w    = t >> 6;           // wave 0..3 -> rows w*16..+15
    int lane = t & 63;
    int lrow = lane & 15;
    int lk   = (lane >> 4) * 8;  // k-chunk within 32

    f32x4 acc[4] = {{0,0,0,0},{0,0,0,0},{0,0,0,0},{0,0,0,0}};
    for (int kt = 0; kt < 4; ++kt) {            // K-step 64
#pragma unroll
        for (int j = 0; j < 4; ++j) {           // stage x: 64 rows x 64 k fp32 -> f16
            int flat = t + j * 256;
            int rr = flat >> 4, c4 = flat & 15;
            int gr = row_base + rr;
            float4 v = (gr < NN) ? x4[(size_t)gr * 64 + kt * 16 + c4]
                                 : make_float4(0.f, 0.f, 0.f, 0.f);
            f16x4 p = {(f16)v.x, (f16)v.y, (f16)v.z, (f16)v.w};
            *(f16x4*)&xl[rr][c4 * 4] = p;
        }
#pragma unroll
        for (int j = 0; j < 2; ++j) {           // stage Wt: 64 cols x 64 k f16
            int flat = t + j * 256;             // 0..511
            int col = flat >> 3, ko = (flat & 7) * 8;
            *(f16x8*)&wl[col][ko] = *(const f16x8*)&wt[col * INF_ + kt * 64 + ko];
        }
        __syncthreads();
        int arow = (w << 4) + lrow;
        f16x8 a0 = *(const f16x8*)&xl[arow][lk];
        f16x8 a1 = *(const f16x8*)&xl[arow][32 + lk];
#pragma unroll
        for (int c = 0; c < 4; ++c) {
            f16x8 b0 = *(const f16x8*)&wl[c * 16 + lrow][lk];
            f16x8 b1 = *(const f16x8*)&wl[c * 16 + lrow][32 + lk];
            acc[c] = __builtin_amdgcn_mfma_f32_16x16x32_f16(a0, b0, acc[c], 0, 0, 0);
            acc[c] = __builtin_amdgcn_mfma_f32_16x16x32_f16(a1, b1, acc[c], 0, 0, 0);
        }
        __syncthreads();
    }
    int orow0 = row_base + (w << 4) + ((lane >> 4) << 2);
#pragma unroll
    for (int c = 0; c < 4; ++c) {
#pragma unroll
        for (int i = 0; i < 4; ++i) {
            int row = orow0 + i;
            if (row < NN) hb[(size_t)row * HID + c * 16 + lrow] = __float2half(acc[c][i]);
        }
    }
}

// ---------------- scan 588 bucket totals ----------------
__global__ __launch_bounds__(256) void k_scan(const u32* __restrict__ bin_total,
                                              u32* __restrict__ binstart) {
    if (threadIdx.x == 0) {
        u32 run = 0;
        for (int i = 0; i < NBIN; ++i) { binstart[i] = run; run += bin_total[i]; }
        binstart[NBIN] = run;
    }
}

// ---------------- scatter edges into bucket-contiguous regions ----------------
__global__ __launch_bounds__(256) void k_scatter(
        const int* __restrict__ ei1, const int* __restrict__ ei2, const int* __restrict__ ei3,
        const float* __restrict__ ew1, const float* __restrict__ ew2, const float* __restrict__ ew3,
        const u32* __restrict__ binstart, const u32* __restrict__ blockbase,
        u64* __restrict__ bucketed) {
    __shared__ u32 cur[NBKT];
    int cb  = blockIdx.x;
    int br  = cb / CBLK;
    int blk = cb - br * CBLK;
    const int*   ei = (br == 0) ? ei1 : (br == 1) ? ei2 : ei3;
    const float* ew = (br == 0) ? ew1 : (br == 1) ? ew2 : ew3;
    int t = threadIdx.x;
    for (int i = t; i < NBKT; i += 256) cur[i] = 0;
    __syncthreads();
    int e0 = blk * 4096;
#pragma unroll
    for (int k = 0; k < 16; ++k) {
        int e = e0 + k * 256 + t;
        if (e < EE) {
            u32 dst = (u32)ei[EE + e];
            u32 src = (u32)ei[e];
            u32 bkt = dst >> 8;
            u32 rnk = atomicAdd(&cur[bkt], 1u);
            u32 pos = binstart[br * NBKT + bkt] + blockbase[cb * NBKT + bkt] + rnk;
            bucketed[pos] = ((u64)__float_as_uint(ew[e]) << 32) | (src << 8) | (dst & 0xffu);
        }
    }
}

// ---------------- per-bucket CSR build, all in LDS ----------------
__global__ __launch_bounds__(256) void k_bucket(
        const u64* __restrict__ bucketed, const u32* __restrict__ bin_total,
        const u32* __restrict__ binstart,
        int* __restrict__ cnt, int* __restrict__ start, float* __restrict__ dinv,
        u32* __restrict__ csr) {
    __shared__ u32   scnt[256];
    __shared__ float swsum[256];
    __shared__ u32   scur[256];
    __shared__ u32   sscan[256];
    __shared__ u32   lcsr[MAXB];
    int bin = blockIdx.x;
    int br  = bin / NBKT;
    int bkt = bin - br * NBKT;
    int t = threadIdx.x;
    u32 base = binstart[bin];
    u32 ecnt = bin_total[bin];
    scnt[t] = 0; swsum[t] = 0.f; scur[t] = 0;
    __syncthreads();
    for (u32 i = t; i < ecnt; i += 256) {
        u64 e = bucketed[base + i];
        u32 dl = (u32)e & 0xffu;
        atomicAdd(&scnt[dl], 1u);
        atomicAdd(&swsum[dl], __uint_as_float((u32)(e >> 32)));
    }
    __syncthreads();
    sscan[t] = scnt[t];
    __syncthreads();
    for (int d = 1; d < 256; d <<= 1) {
        u32 v = (t >= d) ? sscan[t - d] : 0;
        __syncthreads();
        sscan[t] += v;
        __syncthreads();
    }
    u32 lstart = sscan[t] - scnt[t];
    int n = bkt * 256 + t;
    if (n < NN) {
        int gi = br * NN + n;
        cnt[gi]   = (int)scnt[t];
        start[gi] = (int)(base + lstart);
        dinv[gi]  = rsqrtf(1.0f + swsum[t]);
    }
    __syncthreads();
    for (u32 i = t; i < ecnt; i += 256) {
        u64 e = bucketed[base + i];
        u32 dl  = (u32)e & 0xffu;
        u32 src = (u32)(e >> 8) & 0xffffu;
        float w = __uint_as_float((u32)(e >> 32));
        u32 rnk = atomicAdd(&scur[dl], 1u);
        u32 ls  = sscan[dl] - scnt[dl];
        lcsr[ls + rnk] = ((u32)__half_as_ushort(__float2half(w)) << 16) | src;
    }
    __syncthreads();
    for (u32 i = t; i < ecnt; i += 256) csr[base + i] = lcsr[i];
}

// ---------------- rescale csr weights by dinv[src] ----------------
__global__ __launch_bounds__(256) void k_rescale(u32* __restrict__ csr,
                                                 const float* __restrict__ dinv) {
    int i = blockIdx.x * 256 + threadIdx.x;
    int br = i / EE;
    u32 e = csr[i];
    u32 src = e & 0xffffu;
    float w = __half2float(__ushort_as_half((u16)(e >> 16)));
    float nw = w * dinv[br * NN + src];
    csr[i] = ((u32)__half_as_ushort(__float2half(nw)) << 16) | src;
}

// ---------------- fused layer-1 agg (half2 gather, 2 edges/instr) + attention ----------------
__global__ __launch_bounds__(256) void k_agg_attn(
        const u32* __restrict__ csr, const int* __restrict__ start, const int* __restrict__ cnt,
        const float* __restrict__ dinv,
        const float* __restrict__ b1, const float* __restrict__ b2, const float* __restrict__ b3,
        const __half* __restrict__ h,
        const float* __restrict__ fc_w, const float* __restrict__ fc_b,
        __half* __restrict__ comb, float* __restrict__ coef_out) {
    int t   = threadIdx.x;
    int f2  = t & 31;            // feature-pair 0..31
    int eo  = (t >> 5) & 1;      // edge slot 0/1
    int sub = __builtin_amdgcn_readfirstlane(t >> 6);
    int n   = blockIdx.x * 4 + sub;
    float2 wv = ((const float2*)fc_w)[f2];
    float fb = fc_b[0];

    float2 ev[3];
    float c[3];
#pragma unroll
    for (int b = 0; b < 3; ++b) {
        const float* bi = (b == 0) ? b1 : (b == 1) ? b2 : b3;
        const __half2* hb2 = (const __half2*)(h + (size_t)b * NN * HID);
        int i  = b * NN + n;
        int cc = cnt[i];
        int st = start[i];
        float d = dinv[i];
        float2 hs = __half22float2(hb2[(size_t)n * 32 + f2]);

        float ax = 0.f, ay = 0.f;
        int j = 0;
        for (; j + 16 <= cc; j += 16) {          // 8 instr x 2 edges = 16 edges in flight
            u32 ee[8]; __half2 vv[8];
#pragma unroll
            for (int u = 0; u < 8; ++u) ee[u] = csr[st + j + 2 * u + eo];
#pragma unroll
            for (int u = 0; u < 8; ++u)
                vv[u] = hb2[(size_t)(ee[u] & 0xffff) * 32 + f2];
#pragma unroll
            for (int u = 0; u < 8; ++u) {
                float w = __half2float(__ushort_as_half((u16)(ee[u] >> 16)));
                float2 v = __half22float2(vv[u]);
                ax = fmaf(w, v.x, ax);
                ay = fmaf(w, v.y, ay);
            }
        }
        for (; j < cc; j += 2) {
            int jj = j + eo;
            if (jj < cc) {
                u32 e0 = csr[st + jj];
                float w = __half2float(__ushort_as_half((u16)(e0 >> 16)));
                float2 v = __half22float2(hb2[(size_t)(e0 & 0xffff) * 32 + f2]);
                ax = fmaf(w, v.x, ax);
                ay = fmaf(w, v.y, ay);
            }
        }
        ax += __shfl_xor(ax, 32);                // sum the two edge slots
        ay += __shfl_xor(ay, 32);
        float2 bv = ((const float2*)bi)[f2];
        float ex = fmaxf(bv.x + d * d * hs.x + d * ax, 0.f);
        float ey = fmaxf(bv.y + d * d * hs.y + d * ay, 0.f);
        ev[b] = make_float2(ex, ey);

        float dd = ex * wv.x + ey * wv.y;
#pragma unroll
        for (int off = 16; off > 0; off >>= 1) dd += __shfl_xor(dd, off);
        float z = dd + fb;
        z = (z > 0.f) ? z : 0.01f * z;
        c[b] = expf(z);
    }
    float cd = c[0] + c[1] + c[2];
    float coef0 = c[0] / cd, coef1 = c[1] / cd, coef2 = c[2] / cd;
    float cx = ev[0].x * coef0 + ev[1].x * coef1 + ev[2].x * coef2;
    float cy = ev[0].y * coef0 + ev[1].y * coef1 + ev[2].y * coef2;
    if (eo == 0)
        ((__half2*)comb)[(size_t)n * 32 + f2] = __float22half2_rn(make_float2(cx, cy));
    if ((t & 63) == 0) {
        coef_out[n]          = coef0;
        coef_out[NN + n]     = coef1;
        coef_out[2 * NN + n] = coef2;
    }
}

// ---------------- layer-2 GEMM: h2[b] = comb @ W_b (fp16 in/out) ----------------
__global__ __launch_bounds__(256) void k_gemm2(
        const __half* __restrict__ comb,
        const float* __restrict__ W11, const float* __restrict__ W22, const float* __restrict__ W33,
        __half* __restrict__ h2) {
    __shared__ float Wls[3][HID][OUTF];   // 24 KB
    __shared__ __half cl[8][HID];         // 1 KB
    int t = threadIdx.x;
    {
        const float4* w40 = reinterpret_cast<const float4*>(W11);
        const float4* w41 = reinterpret_cast<const float4*>(W22);
        const float4* w42 = reinterpret_cast<const float4*>(W33);
        float4* d0 = reinterpret_cast<float4*>(&Wls[0][0][0]);
        float4* d1 = reinterpret_cast<float4*>(&Wls[1][0][0]);
        float4* d2 = reinterpret_cast<float4*>(&Wls[2][0][0]);
#pragma unroll
        for (int j = 0; j < 2; ++j) {
            d0[t + j * 256] = w40[t + j * 256];
            d1[t + j * 256] = w41[t + j * 256];
            d2[t + j * 256] = w42[t + j * 256];
        }
    }
    int row0 = blockIdx.x * 8;                    // 50000 = 6250*8 exact
    ((u32*)cl)[t] = ((const u32*)(comb + (size_t)row0 * HID))[t];
    __syncthreads();

    int col = t & 31;
    int rr  = t >> 5;
    int row = row0 + rr;
    float a0 = 0.f, a1 = 0.f, a2 = 0.f;
    for (int k = 0; k < HID; ++k) {
        float cv = __half2float(cl[rr][k]);
        a0 = fmaf(cv, Wls[0][k][col], a0);
        a1 = fmaf(cv, Wls[1][k][col], a1);
        a2 = fmaf(cv, Wls[2][k][col], a2);
    }
    h2[(size_t)0 * NN * OUTF + (size_t)row * OUTF + col] = __float2half(a0);
    h2[(size_t)1 * NN * OUTF + (size_t)row * OUTF + col] = __float2half(a1);
    h2[(size_t)2 * NN * OUTF + (size_t)row * OUTF + col] = __float2half(a2);
}

// ---------------- layer-2 aggregation: half2 gather, 4 edges/instr ----------------
__global__ __launch_bounds__(256) void k_agg2(
        const u32* __restrict__ csr, const int* __restrict__ start, const int* __restrict__ cnt,
        const float* __restrict__ dinv,
        const float* __restrict__ b11, const float* __restrict__ b22, const float* __restrict__ b33,
        const __half* __restrict__ h2, float* __restrict__ out) {
    int t   = threadIdx.x;
    int f2  = t & 15;            // feature-pair 0..15
    int eo  = (t >> 4) & 3;      // edge slot 0..3
    int sub = __builtin_amdgcn_readfirstlane(t >> 6);
    int n   = blockIdx.x * 4 + sub;

    float2 bA = ((const float2*)b11)[f2];
    float2 bB = ((const float2*)b22)[f2];
    float2 bC = ((const float2*)b33)[f2];
    float tx = bA.x + bB.x + bC.x;
    float ty = bA.y + bB.y + bC.y;
#pragma unroll
    for (int b = 0; b < 3; ++b) {
        int i  = b * NN + n;
        int cc = cnt[i];
        int st = start[i];
        const __half2* h2b = (const __half2*)(h2 + (size_t)b * NN * OUTF);
        float ax = 0.f, ay = 0.f;
        int j = 0;
        for (; j + 16 <= cc; j += 16) {          // 4 instr x 4 edges = 16 in flight
            u32 ee[4]; __half2 vv[4];
#pragma unroll
            for (int u = 0; u < 4; ++u) ee[u] = csr[st + j + 4 * u + eo];
#pragma unroll
            for (int u = 0; u < 4; ++u)
                vv[u] = h2b[(size_t)(ee[u] & 0xffff) * 16 + f2];
#pragma unroll
            for (int u = 0; u < 4; ++u) {
                float w = __half2float(__ushort_as_half((u16)(ee[u] >> 16)));
                float2 v = __half22float2(vv[u]);
                ax = fmaf(w, v.x, ax);
                ay = fmaf(w, v.y, ay);
            }
        }
        for (; j < cc; j += 4) {
            int jj = j + eo;
            if (jj < cc) {
                u32 e0 = csr[st + jj];
                float w = __half2float(__ushort_as_half((u16)(e0 >> 16)));
                float2 v = __half22float2(h2b[(size_t)(e0 & 0xffff) * 16 + f2]);
                ax = fmaf(w, v.x, ax);
                ay = fmaf(w, v.y, ay);
            }
        }
        ax += __shfl_xor(ax, 16); ay += __shfl_xor(ay, 16);
        ax += __shfl_xor(ax, 32); ay += __shfl_xor(ay, 32);
        float d = dinv[i];
        float2 hs = __half22float2(h2b[(size_t)n * 16 + f2]);
        tx += d * ax + d * d * hs.x;
        ty += d * ay + d * d * hs.y;
    }
    if (eo == 0)
        ((float2*)out)[(size_t)n * 16 + f2] = make_float2(tx, ty);
}

// ---------------- launch ----------------
extern "C" void kernel_launch(void* const* d_in, const int* in_sizes, int n_in,
                              void* d_out, int out_size, void* d_ws, size_t ws_size,
                              hipStream_t stream) {
    const float* x1  = (const float*)d_in[0];
    const float* x2  = (const float*)d_in[1];
    const float* x3  = (const float*)d_in[2];
    const int*   ei1 = (const int*)d_in[3];
    const int*   ei2 = (const int*)d_in[4];
    const int*   ei3 = (const int*)d_in[5];
    const float* ew1 = (const float*)d_in[6];
    const float* ew2 = (const float*)d_in[7];
    const float* ew3 = (const float*)d_in[8];
    const float* W1  = (const float*)d_in[9];
    const float* W2  = (const float*)d_in[10];
    const float* W3  = (const float*)d_in[11];
    const float* b1  = (const float*)d_in[12];
    const float* b2  = (const float*)d_in[13];
    const float* b3  = (const float*)d_in[14];
    const float* fcw = (const float*)d_in[15];
    const float* fcb = (const float*)d_in[16];
    const float* W11 = (const float*)d_in[17];
    const float* W22 = (const float*)d_in[18];
    const float* W33 = (const float*)d_in[19];
    const float* b11 = (const float*)d_in[20];
    const float* b22 = (const float*)d_in[21];
    const float* b33 = (const float*)d_in[22];

    float* out = (float*)d_out;
    float* coef_out = out + (size_t)NN * OUTF;

    // workspace layout (all 16B-aligned)
    u64*   bucketed  = (u64*)d_ws;                           // 3E u64   19.2 MB
    u32*   csr       = (u32*)(bucketed + 3 * EE);            // 3E u32    9.6 MB
    u32*   bin_total = csr + 3 * EE;                         // 588
    u32*   binstart  = bin_total + NBIN;                     // 592
    u32*   blockbase = binstart + NBIN + 4;                  // 588*196
    float* dinv      = (float*)(blockbase + NCNT * NBKT);    // 3N
    int*   cnt       = (int*)(dinv + TOTN);                  // 3N
    int*   start     = cnt + TOTN;                           // 3N
    f16*   Wt        = (f16*)(start + TOTN);                 // 3*64*256 f16 96 KB
    __half* h        = (__half*)(Wt + 3 * HID * INF_);       // 3N*64    19.2 MB
    __half* comb     = h + (size_t)TOTN * HID;               // N*64      6.4 MB
    __half* h2       = comb + (size_t)NN * HID;              // 3N*32     9.6 MB

    k_prep<<<dim3(4), 256, 0, stream>>>(W1, W2, W3, Wt, bin_total);
    k_cntgemm<<<dim3(NCNT * 5), 256, 0, stream>>>(ei1, ei2, ei3, bin_total, blockbase,
                                                  x1, x2, x3, Wt, h);
    k_scan<<<dim3(1), 256, 0, stream>>>(bin_total, binstart);
    k_scatter<<<dim3(NCNT), 256, 0, stream>>>(ei1, ei2, ei3, ew1, ew2, ew3,
                                              binstart, blockbase, bucketed);
    k_bucket<<<dim3(NBIN), 256, 0, stream>>>(bucketed, bin_total, binstart,
                                             cnt, start, dinv, csr);
    k_rescale<<<dim3(3 * EE / 256), 256, 0, stream>>>(csr, dinv);

    k_agg_attn<<<dim3(NN / 4), 256, 0, stream>>>(csr, start, cnt, dinv, b1, b2, b3,
                                                 h, fcw, fcb, comb, coef_out);
    k_gemm2<<<dim3(NN / 8), 256, 0, stream>>>(comb, W11, W22, W33, h2);
    k_agg2<<<dim3(NN / 4), 256, 0, stream>>>(csr, start, cnt, dinv,
                                             b11, b22, b33, h2, out);
}

// Round 10
// 293.906 us; speedup vs baseline: 1.5230x; 1.1490x over previous
//
#include <hip/hip_runtime.h>
#include <hip/hip_fp16.h>
#include <math.h>

#define NN    50000
#define INF_  256
#define HID   64
#define OUTF  32
#define EE    800000
#define TOTN  (3 * NN)
#define NBKT  196            // buckets per branch (256 dst nodes each)
#define NBIN  (3 * NBKT)     // 588
#define CBLK  392            // count/scatter blocks per branch (2048 edges each)
#define NCNT  (3 * CBLK)     // 1176
#define GB    782            // gemm tiles per branch (64 rows)
#define NGEMM (3 * GB)       // 2346
#define MAXB  5120

typedef unsigned long long u64;
typedef unsigned int       u32;
typedef unsigned short     u16;
typedef _Float16           f16;
typedef f16   f16x8 __attribute__((ext_vector_type(8)));
typedef f16   f16x4 __attribute__((ext_vector_type(4)));
typedef float f32x4 __attribute__((ext_vector_type(4)));

// ---------------- prep: zero bin totals + transpose/convert W -> Wt fp16 [col][k] ----------------
__global__ __launch_bounds__(256) void k_prep(
        const float* __restrict__ W1, const float* __restrict__ W2, const float* __restrict__ W3,
        f16* __restrict__ Wt, u32* __restrict__ bin_total) {
    int blk = blockIdx.x, t = threadIdx.x;
    if (blk == 3) {
        for (int i = t; i < NBIN; i += 256) bin_total[i] = 0;
        return;
    }
    const float* W = (blk == 0) ? W1 : (blk == 1) ? W2 : W3;
    f16* wt = Wt + blk * HID * INF_;
    for (int idx = t; idx < INF_ * HID; idx += 256) {
        int k = idx >> 6, c = idx & 63;
        wt[c * INF_ + k] = (f16)W[idx];
    }
}

// ---------------- fused: bucket-count + MFMA fp16 layer-1 GEMM, 2:1 interleave ----------------
// period 3: r<2 -> gemm gid=2q+r; r==2 -> count cid=q.
__global__ __launch_bounds__(256) void k_cntgemm(
        const int* __restrict__ ei1, const int* __restrict__ ei2, const int* __restrict__ ei3,
        u32* __restrict__ bin_total, u32* __restrict__ blockbase,
        const float* __restrict__ x1, const float* __restrict__ x2, const float* __restrict__ x3,
        const f16* __restrict__ Wt, __half* __restrict__ h) {
    __shared__ f16 xl[64][72];   // 9.2 KB
    __shared__ f16 wl[64][72];   // 9.2 KB
    int bid = blockIdx.x;
    int q = bid / 3, r = bid - q * 3;
    int t = threadIdx.x;

    if (r == 2) {                   // ---- count block: q in [0,1176) ----
        u32* bins = (u32*)xl;
        int cb  = q;
        int br  = cb / CBLK;
        int blk = cb - br * CBLK;
        const int* ei = (br == 0) ? ei1 : (br == 1) ? ei2 : ei3;
        for (int i = t; i < NBKT; i += 256) bins[i] = 0;
        __syncthreads();
        int e0 = blk * 2048;
#pragma unroll
        for (int k = 0; k < 8; ++k) {
            int e = e0 + k * 256 + t;
            if (e < EE) atomicAdd(&bins[(u32)ei[EE + e] >> 8], 1u);
        }
        __syncthreads();
        for (int i = t; i < NBKT; i += 256) {
            u32 c = bins[i];
            u32 base = atomicAdd(&bin_total[br * NBKT + i], c);
            blockbase[cb * NBKT + i] = base;
        }
        return;
    }

    // ---- gemm: gid in [0, NGEMM) ----
    int gid = q * 2 + r;
    if (gid >= NGEMM) return;
    int b = gid / GB;
    int row_base = (gid - b * GB) * 64;
    const float4* x4 = reinterpret_cast<const float4*>((b == 0) ? x1 : (b == 1) ? x2 : x3);
    const f16* wt = Wt + b * HID * INF_;
    __half* hb = h + (size_t)b * NN * HID;

    int w    = t >> 6;
    int lane = t & 63;
    int lrow = lane & 15;
    int lk   = (lane >> 4) * 8;

    f32x4 acc[4] = {{0,0,0,0},{0,0,0,0},{0,0,0,0},{0,0,0,0}};
    for (int kt = 0; kt < 4; ++kt) {
#pragma unroll
        for (int j = 0; j < 4; ++j) {
            int flat = t + j * 256;
            int rr = flat >> 4, c4 = flat & 15;
            int gr = row_base + rr;
            float4 v = (gr < NN) ? x4[(size_t)gr * 64 + kt * 16 + c4]
                                 : make_float4(0.f, 0.f, 0.f, 0.f);
            f16x4 p = {(f16)v.x, (f16)v.y, (f16)v.z, (f16)v.w};
            *(f16x4*)&xl[rr][c4 * 4] = p;
        }
#pragma unroll
        for (int j = 0; j < 2; ++j) {
            int flat = t + j * 256;
            int col = flat >> 3, ko = (flat & 7) * 8;
            *(f16x8*)&wl[col][ko] = *(const f16x8*)&wt[col * INF_ + kt * 64 + ko];
        }
        __syncthreads();
        int arow = (w << 4) + lrow;
        f16x8 a0 = *(const f16x8*)&xl[arow][lk];
        f16x8 a1 = *(const f16x8*)&xl[arow][32 + lk];
#pragma unroll
        for (int c = 0; c < 4; ++c) {
            f16x8 b0 = *(const f16x8*)&wl[c * 16 + lrow][lk];
            f16x8 b1 = *(const f16x8*)&wl[c * 16 + lrow][32 + lk];
            acc[c] = __builtin_amdgcn_mfma_f32_16x16x32_f16(a0, b0, acc[c], 0, 0, 0);
            acc[c] = __builtin_amdgcn_mfma_f32_16x16x32_f16(a1, b1, acc[c], 0, 0, 0);
        }
        __syncthreads();
    }
    int orow0 = row_base + (w << 4) + ((lane >> 4) << 2);
#pragma unroll
    for (int c = 0; c < 4; ++c) {
#pragma unroll
        for (int i = 0; i < 4; ++i) {
            int row = orow0 + i;
            if (row < NN) hb[(size_t)row * HID + c * 16 + lrow] = __float2half(acc[c][i]);
        }
    }
}

// ---------------- parallel scan of 588 bucket totals (1 block) ----------------
__global__ __launch_bounds__(256) void k_scan(const u32* __restrict__ bin_total,
                                              u32* __restrict__ binstart) {
    __shared__ u32 s[256];
    int t = threadIdx.x;
    u32 c[3]; u32 sum = 0;
#pragma unroll
    for (int k = 0; k < 3; ++k) {
        int i = t * 3 + k;
        c[k] = (i < NBIN) ? bin_total[i] : 0;
        sum += c[k];
    }
    s[t] = sum;
    __syncthreads();
    for (int d = 1; d < 256; d <<= 1) {
        u32 v = (t >= d) ? s[t - d] : 0;
        __syncthreads();
        s[t] += v;
        __syncthreads();
    }
    u32 run = s[t] - sum;
#pragma unroll
    for (int k = 0; k < 3; ++k) {
        int i = t * 3 + k;
        if (i < NBIN) binstart[i] = run;
        run += c[k];
    }
    if (t == 255) binstart[NBIN] = run;
}

// ---------------- scatter edges into bucket-contiguous regions ----------------
__global__ __launch_bounds__(256) void k_scatter(
        const int* __restrict__ ei1, const int* __restrict__ ei2, const int* __restrict__ ei3,
        const float* __restrict__ ew1, const float* __restrict__ ew2, const float* __restrict__ ew3,
        const u32* __restrict__ binstart, const u32* __restrict__ blockbase,
        u64* __restrict__ bucketed) {
    __shared__ u32 cur[NBKT];
    int cb  = blockIdx.x;            // 0..1175
    int br  = cb / CBLK;
    int blk = cb - br * CBLK;
    const int*   ei = (br == 0) ? ei1 : (br == 1) ? ei2 : ei3;
    const float* ew = (br == 0) ? ew1 : (br == 1) ? ew2 : ew3;
    int t = threadIdx.x;
    for (int i = t; i < NBKT; i += 256) cur[i] = 0;
    __syncthreads();
    int e0 = blk * 2048;
#pragma unroll
    for (int k = 0; k < 8; ++k) {
        int e = e0 + k * 256 + t;
        if (e < EE) {
            u32 dst = (u32)ei[EE + e];
            u32 src = (u32)ei[e];
            u32 bkt = dst >> 8;
            u32 rnk = atomicAdd(&cur[bkt], 1u);
            u32 pos = binstart[br * NBKT + bkt] + blockbase[cb * NBKT + bkt] + rnk;
            bucketed[pos] = ((u64)__float_as_uint(ew[e]) << 32) | (src << 8) | (dst & 0xffu);
        }
    }
}

// ---------------- per-bucket: nodeinfo/dinv/CSR in LDS + h-prescale of owned rows ----------------
__global__ __launch_bounds__(256) void k_bucket(
        const u64* __restrict__ bucketed, const u32* __restrict__ bin_total,
        const u32* __restrict__ binstart,
        u32* __restrict__ nodeinfo, float* __restrict__ dinv,
        u32* __restrict__ csr, __half* __restrict__ h) {
    __shared__ u32   scnt[256];
    __shared__ float swsum[256];
    __shared__ u32   scur[256];
    __shared__ u32   sscan[256];
    __shared__ float sdiv[256];
    __shared__ u32   lcsr[MAXB];
    int bin = blockIdx.x;
    int br  = bin / NBKT;
    int bkt = bin - br * NBKT;
    int t = threadIdx.x;
    u32 base = binstart[bin];
    u32 ecnt = bin_total[bin];
    scnt[t] = 0; swsum[t] = 0.f; scur[t] = 0;
    __syncthreads();
    for (u32 i = t; i < ecnt; i += 256) {
        u64 e = bucketed[base + i];
        u32 dl = (u32)e & 0xffu;
        atomicAdd(&scnt[dl], 1u);
        atomicAdd(&swsum[dl], __uint_as_float((u32)(e >> 32)));
    }
    __syncthreads();
    sscan[t] = scnt[t];
    __syncthreads();
    for (int d = 1; d < 256; d <<= 1) {
        u32 v = (t >= d) ? sscan[t - d] : 0;
        __syncthreads();
        sscan[t] += v;
        __syncthreads();
    }
    u32 lstart = sscan[t] - scnt[t];
    float d = rsqrtf(1.0f + swsum[t]);
    sdiv[t] = d;
    int n = bkt * 256 + t;
    if (n < NN) {
        int gi = br * NN + n;
        nodeinfo[gi] = ((base + lstart) << 10) | scnt[t];
        dinv[gi]     = d;
    }
    __syncthreads();
    for (u32 i = t; i < ecnt; i += 256) {
        u64 e = bucketed[base + i];
        u32 dl  = (u32)e & 0xffu;
        u32 src = (u32)(e >> 8) & 0xffffu;
        float w = __uint_as_float((u32)(e >> 32));
        u32 rnk = atomicAdd(&scur[dl], 1u);
        u32 ls  = sscan[dl] - scnt[dl];
        lcsr[ls + rnk] = ((u32)__half_as_ushort(__float2half(w)) << 16) | src;
    }
    __syncthreads();
    for (u32 i = t; i < ecnt; i += 256) csr[base + i] = lcsr[i];

    // ---- prescale h rows owned by this bucket: h'[n] = dinv[n] * h[n] (coalesced) ----
    int nrows = NN - bkt * 256; if (nrows > 256) nrows = 256;
    u32* hrow = (u32*)(h + ((size_t)br * NN + (size_t)bkt * 256) * HID);
    for (int i = t; i < nrows * 32; i += 256) {
        float dd = sdiv[i >> 5];
        __half2 hv = *(__half2*)&hrow[i];
        float2 v = __half22float2(hv);
        __half2 r = __float22half2_rn(make_float2(v.x * dd, v.y * dd));
        hrow[i] = *(u32*)&r;
    }
}

// ---------------- fused layer-1 agg (batched clamped gathers) + attention ----------------
__global__ __launch_bounds__(256) void k_agg_attn(
        const u32* __restrict__ csr, const u32* __restrict__ nodeinfo,
        const float* __restrict__ dinv,
        const float* __restrict__ b1, const float* __restrict__ b2, const float* __restrict__ b3,
        const __half* __restrict__ h,
        const float* __restrict__ fc_w, const float* __restrict__ fc_b,
        __half* __restrict__ comb, float* __restrict__ coef_out) {
    int t   = threadIdx.x;
    int f2  = t & 31;
    int eo  = (t >> 5) & 1;
    int sub = __builtin_amdgcn_readfirstlane(t >> 6);
    int n   = blockIdx.x * 4 + sub;
    float2 wv = ((const float2*)fc_w)[f2];
    float fb = fc_b[0];

    float2 ev[3];
    float c[3];
#pragma unroll
    for (int b = 0; b < 3; ++b) {
        const float* bi = (b == 0) ? b1 : (b == 1) ? b2 : b3;
        const __half2* hb2 = (const __half2*)(h + (size_t)b * NN * HID);
        int i   = b * NN + n;
        u32 inf = nodeinfo[i];
        int cc  = (int)(inf & 1023u);
        int st  = (int)(inf >> 10);
        float d = dinv[i];
        float2 hs = __half22float2(hb2[(size_t)n * 32 + f2]);

        float ax = 0.f, ay = 0.f;
        int cm1 = cc - 1;
        for (int j = 0; j < cc; j += 16) {       // all loads issued before any FMA
            u32 ee[8]; __half2 vv[8];
#pragma unroll
            for (int u = 0; u < 8; ++u) {
                int jj = j + 2 * u + eo;
                ee[u] = csr[st + (jj < cm1 ? jj : cm1)];
                if (jj >= cc) ee[u] &= 0xffffu;  // zero weight for padded lanes
            }
#pragma unroll
            for (int u = 0; u < 8; ++u)
                vv[u] = hb2[(size_t)(ee[u] & 0xffff) * 32 + f2];
#pragma unroll
            for (int u = 0; u < 8; ++u) {
                float w = __half2float(__ushort_as_half((u16)(ee[u] >> 16)));
                float2 v = __half22float2(vv[u]);
                ax = fmaf(w, v.x, ax);
                ay = fmaf(w, v.y, ay);
            }
        }
        ax += __shfl_xor(ax, 32);
        ay += __shfl_xor(ay, 32);
        float2 bv = ((const float2*)bi)[f2];
        float ex = fmaxf(bv.x + d * (hs.x + ax), 0.f);   // h already dinv-scaled
        float ey = fmaxf(bv.y + d * (hs.y + ay), 0.f);
        ev[b] = make_float2(ex, ey);

        float dd = ex * wv.x + ey * wv.y;
#pragma unroll
        for (int off = 16; off > 0; off >>= 1) dd += __shfl_xor(dd, off);
        float z = dd + fb;
        z = (z > 0.f) ? z : 0.01f * z;
        c[b] = expf(z);
    }
    float cd = c[0] + c[1] + c[2];
    float coef0 = c[0] / cd, coef1 = c[1] / cd, coef2 = c[2] / cd;
    float cx = ev[0].x * coef0 + ev[1].x * coef1 + ev[2].x * coef2;
    float cy = ev[0].y * coef0 + ev[1].y * coef1 + ev[2].y * coef2;
    if (eo == 0)
        ((__half2*)comb)[(size_t)n * 32 + f2] = __float22half2_rn(make_float2(cx, cy));
    if ((t & 63) == 0) {
        coef_out[n]          = coef0;
        coef_out[NN + n]     = coef1;
        coef_out[2 * NN + n] = coef2;
    }
}

// ---------------- layer-2 GEMM: h2'[b] = dinv * (comb @ W_b) ----------------
__global__ __launch_bounds__(256) void k_gemm2(
        const __half* __restrict__ comb,
        const float* __restrict__ W11, const float* __restrict__ W22, const float* __restrict__ W33,
        const float* __restrict__ dinv, __half* __restrict__ h2) {
    __shared__ float Wls[3][HID][OUTF];
    __shared__ __half cl[8][HID];
    int t = threadIdx.x;
    {
        const float4* w40 = reinterpret_cast<const float4*>(W11);
        const float4* w41 = reinterpret_cast<const float4*>(W22);
        const float4* w42 = reinterpret_cast<const float4*>(W33);
        float4* d0 = reinterpret_cast<float4*>(&Wls[0][0][0]);
        float4* d1 = reinterpret_cast<float4*>(&Wls[1][0][0]);
        float4* d2 = reinterpret_cast<float4*>(&Wls[2][0][0]);
#pragma unroll
        for (int j = 0; j < 2; ++j) {
            d0[t + j * 256] = w40[t + j * 256];
            d1[t + j * 256] = w41[t + j * 256];
            d2[t + j * 256] = w42[t + j * 256];
        }
    }
    int row0 = blockIdx.x * 8;
    ((u32*)cl)[t] = ((const u32*)(comb + (size_t)row0 * HID))[t];
    __syncthreads();

    int col = t & 31;
    int rr  = t >> 5;
    int row = row0 + rr;
    float a0 = 0.f, a1 = 0.f, a2 = 0.f;
    for (int k = 0; k < HID; ++k) {
        float cv = __half2float(cl[rr][k]);
        a0 = fmaf(cv, Wls[0][k][col], a0);
        a1 = fmaf(cv, Wls[1][k][col], a1);
        a2 = fmaf(cv, Wls[2][k][col], a2);
    }
    float d0 = dinv[row], d1 = dinv[NN + row], d2 = dinv[2 * NN + row];
    h2[(size_t)0 * NN * OUTF + (size_t)row * OUTF + col] = __float2half(a0 * d0);
    h2[(size_t)1 * NN * OUTF + (size_t)row * OUTF + col] = __float2half(a1 * d1);
    h2[(size_t)2 * NN * OUTF + (size_t)row * OUTF + col] = __float2half(a2 * d2);
}

// ---------------- layer-2 aggregation: batched clamped gathers ----------------
__global__ __launch_bounds__(256) void k_agg2(
        const u32* __restrict__ csr, const u32* __restrict__ nodeinfo,
        const float* __restrict__ dinv,
        const float* __restrict__ b11, const float* __restrict__ b22, const float* __restrict__ b33,
        const __half* __restrict__ h2, float* __restrict__ out) {
    int t   = threadIdx.x;
    int f2  = t & 15;
    int eo  = (t >> 4) & 3;
    int sub = __builtin_amdgcn_readfirstlane(t >> 6);
    int n   = blockIdx.x * 4 + sub;

    float2 bA = ((const float2*)b11)[f2];
    float2 bB = ((const float2*)b22)[f2];
    float2 bC = ((const float2*)b33)[f2];
    float tx = bA.x + bB.x + bC.x;
    float ty = bA.y + bB.y + bC.y;
#pragma unroll
    for (int b = 0; b < 3; ++b) {
        int i   = b * NN + n;
        u32 inf = nodeinfo[i];
        int cc  = (int)(inf & 1023u);
        int st  = (int)(inf >> 10);
        const __half2* h2b = (const __half2*)(h2 + (size_t)b * NN * OUTF);
        float ax = 0.f, ay = 0.f;
        int cm1 = cc - 1;
        for (int j = 0; j < cc; j += 16) {
            u32 ee[4]; __half2 vv[4];
#pragma unroll
            for (int u = 0; u < 4; ++u) {
                int jj = j + 4 * u + eo;
                ee[u] = csr[st + (jj < cm1 ? jj : cm1)];
                if (jj >= cc) ee[u] &= 0xffffu;
            }
#pragma unroll
            for (int u = 0; u < 4; ++u)
                vv[u] = h2b[(size_t)(ee[u] & 0xffff) * 16 + f2];
#pragma unroll
            for (int u = 0; u < 4; ++u) {
                float w = __half2float(__ushort_as_half((u16)(ee[u] >> 16)));
                float2 v = __half22float2(vv[u]);
                ax = fmaf(w, v.x, ax);
                ay = fmaf(w, v.y, ay);
            }
        }
        ax += __shfl_xor(ax, 16); ay += __shfl_xor(ay, 16);
        ax += __shfl_xor(ax, 32); ay += __shfl_xor(ay, 32);
        float d = dinv[i];
        float2 hs = __half22float2(h2b[(size_t)n * 16 + f2]);   // already dinv-scaled
        tx += d * (ax + hs.x);
        ty += d * (ay + hs.y);
    }
    if (eo == 0)
        ((float2*)out)[(size_t)n * 16 + f2] = make_float2(tx, ty);
}

// ---------------- launch ----------------
extern "C" void kernel_launch(void* const* d_in, const int* in_sizes, int n_in,
                              void* d_out, int out_size, void* d_ws, size_t ws_size,
                              hipStream_t stream) {
    const float* x1  = (const float*)d_in[0];
    const float* x2  = (const float*)d_in[1];
    const float* x3  = (const float*)d_in[2];
    const int*   ei1 = (const int*)d_in[3];
    const int*   ei2 = (const int*)d_in[4];
    const int*   ei3 = (const int*)d_in[5];
    const float* ew1 = (const float*)d_in[6];
    const float* ew2 = (const float*)d_in[7];
    const float* ew3 = (const float*)d_in[8];
    const float* W1  = (const float*)d_in[9];
    const float* W2  = (const float*)d_in[10];
    const float* W3  = (const float*)d_in[11];
    const float* b1  = (const float*)d_in[12];
    const float* b2  = (const float*)d_in[13];
    const float* b3  = (const float*)d_in[14];
    const float* fcw = (const float*)d_in[15];
    const float* fcb = (const float*)d_in[16];
    const float* W11 = (const float*)d_in[17];
    const float* W22 = (const float*)d_in[18];
    const float* W33 = (const float*)d_in[19];
    const float* b11 = (const float*)d_in[20];
    const float* b22 = (const float*)d_in[21];
    const float* b33 = (const float*)d_in[22];

    float* out = (float*)d_out;
    float* coef_out = out + (size_t)NN * OUTF;

    // workspace layout
    u64*   bucketed  = (u64*)d_ws;                           // 3E u64   19.2 MB
    u32*   csr       = (u32*)(bucketed + 3 * EE);            // 3E u32    9.6 MB
    u32*   bin_total = csr + 3 * EE;                         // 588
    u32*   binstart  = bin_total + NBIN;                     // 592
    u32*   blockbase = binstart + NBIN + 4;                  // 1176*196  922 KB
    float* dinv      = (float*)(blockbase + NCNT * NBKT);    // 3N
    u32*   nodeinfo  = (u32*)(dinv + TOTN);                  // 3N
    f16*   Wt        = (f16*)(nodeinfo + TOTN);              // 3*64*256
    __half* h        = (__half*)(Wt + 3 * HID * INF_);       // 3N*64    19.2 MB
    __half* comb     = h + (size_t)TOTN * HID;               // N*64      6.4 MB
    __half* h2       = comb + (size_t)NN * HID;              // 3N*32     9.6 MB

    k_prep<<<dim3(4), 256, 0, stream>>>(W1, W2, W3, Wt, bin_total);
    k_cntgemm<<<dim3(NCNT * 3), 256, 0, stream>>>(ei1, ei2, ei3, bin_total, blockbase,
                                                  x1, x2, x3, Wt, h);
    k_scan<<<dim3(1), 256, 0, stream>>>(bin_total, binstart);
    k_scatter<<<dim3(NCNT), 256, 0, stream>>>(ei1, ei2, ei3, ew1, ew2, ew3,
                                              binstart, blockbase, bucketed);
    k_bucket<<<dim3(NBIN), 256, 0, stream>>>(bucketed, bin_total, binstart,
                                             nodeinfo, dinv, csr, h);

    k_agg_attn<<<dim3(NN / 4), 256, 0, stream>>>(csr, nodeinfo, dinv, b1, b2, b3,
                                                 h, fcw, fcb, comb, coef_out);
    k_gemm2<<<dim3(NN / 8), 256, 0, stream>>>(comb, W11, W22, W33, dinv, h2);
    k_agg2<<<dim3(NN / 4), 256, 0, stream>>>(csr, nodeinfo, dinv,
                                             b11, b22, b33, h2, out);
}

// Round 11
// 290.651 us; speedup vs baseline: 1.5401x; 1.0112x over previous
//
#include <hip/hip_runtime.h>
#include <hip/hip_fp16.h>
#include <math.h>

#define NN    50000
#define INF_  256
#define HID   64
#define OUTF  32
#define EE    800000
#define TOTN  (3 * NN)
#define NBKT  196
#define NBIN  (3 * NBKT)     // 588
#define CBLK  392
#define NCNT  (3 * CBLK)     // 1176
#define GB    782
#define NGEMM (3 * GB)       // 2346
#define MAXB  5120
#define NBLK  12500          // node-blocks per branch (4 nodes each)

typedef unsigned long long u64;
typedef unsigned int       u32;
typedef unsigned short     u16;
typedef _Float16           f16;
typedef f16   f16x8 __attribute__((ext_vector_type(8)));
typedef f16   f16x4 __attribute__((ext_vector_type(4)));
typedef float f32x4 __attribute__((ext_vector_type(4)));

// ---------------- prep: zero bin totals + transpose/convert W -> Wt fp16 [col][k] ----------------
__global__ __launch_bounds__(256) void k_prep(
        const float* __restrict__ W1, const float* __restrict__ W2, const float* __restrict__ W3,
        f16* __restrict__ Wt, u32* __restrict__ bin_total) {
    int blk = blockIdx.x, t = threadIdx.x;
    if (blk == 3) {
        for (int i = t; i < NBIN; i += 256) bin_total[i] = 0;
        return;
    }
    const float* W = (blk == 0) ? W1 : (blk == 1) ? W2 : W3;
    f16* wt = Wt + blk * HID * INF_;
    for (int idx = t; idx < INF_ * HID; idx += 256) {
        int k = idx >> 6, c = idx & 63;
        wt[c * INF_ + k] = (f16)W[idx];
    }
}

// ---------------- fused: bucket-count + MFMA fp16 layer-1 GEMM, 2:1 interleave ----------------
__global__ __launch_bounds__(256) void k_cntgemm(
        const int* __restrict__ ei1, const int* __restrict__ ei2, const int* __restrict__ ei3,
        u32* __restrict__ bin_total, u32* __restrict__ blockbase,
        const float* __restrict__ x1, const float* __restrict__ x2, const float* __restrict__ x3,
        const f16* __restrict__ Wt, __half* __restrict__ h) {
    __shared__ f16 xl[64][72];
    __shared__ f16 wl[64][72];
    int bid = blockIdx.x;
    int q = bid / 3, r = bid - q * 3;
    int t = threadIdx.x;

    if (r == 2) {
        u32* bins = (u32*)xl;
        int cb  = q;
        int br  = cb / CBLK;
        int blk = cb - br * CBLK;
        const int* ei = (br == 0) ? ei1 : (br == 1) ? ei2 : ei3;
        for (int i = t; i < NBKT; i += 256) bins[i] = 0;
        __syncthreads();
        int e0 = blk * 2048;
#pragma unroll
        for (int k = 0; k < 8; ++k) {
            int e = e0 + k * 256 + t;
            if (e < EE) atomicAdd(&bins[(u32)ei[EE + e] >> 8], 1u);
        }
        __syncthreads();
        for (int i = t; i < NBKT; i += 256) {
            u32 c = bins[i];
            u32 base = atomicAdd(&bin_total[br * NBKT + i], c);
            blockbase[cb * NBKT + i] = base;
        }
        return;
    }

    int gid = q * 2 + r;
    if (gid >= NGEMM) return;
    int b = gid / GB;
    int row_base = (gid - b * GB) * 64;
    const float4* x4 = reinterpret_cast<const float4*>((b == 0) ? x1 : (b == 1) ? x2 : x3);
    const f16* wt = Wt + b * HID * INF_;
    __half* hb = h + (size_t)b * NN * HID;

    int w    = t >> 6;
    int lane = t & 63;
    int lrow = lane & 15;
    int lk   = (lane >> 4) * 8;

    f32x4 acc[4] = {{0,0,0,0},{0,0,0,0},{0,0,0,0},{0,0,0,0}};
    for (int kt = 0; kt < 4; ++kt) {
#pragma unroll
        for (int j = 0; j < 4; ++j) {
            int flat = t + j * 256;
            int rr = flat >> 4, c4 = flat & 15;
            int gr = row_base + rr;
            float4 v = (gr < NN) ? x4[(size_t)gr * 64 + kt * 16 + c4]
                                 : make_float4(0.f, 0.f, 0.f, 0.f);
            f16x4 p = {(f16)v.x, (f16)v.y, (f16)v.z, (f16)v.w};
            *(f16x4*)&xl[rr][c4 * 4] = p;
        }
#pragma unroll
        for (int j = 0; j < 2; ++j) {
            int flat = t + j * 256;
            int col = flat >> 3, ko = (flat & 7) * 8;
            *(f16x8*)&wl[col][ko] = *(const f16x8*)&wt[col * INF_ + kt * 64 + ko];
        }
        __syncthreads();
        int arow = (w << 4) + lrow;
        f16x8 a0 = *(const f16x8*)&xl[arow][lk];
        f16x8 a1 = *(const f16x8*)&xl[arow][32 + lk];
#pragma unroll
        for (int c = 0; c < 4; ++c) {
            f16x8 b0 = *(const f16x8*)&wl[c * 16 + lrow][lk];
            f16x8 b1 = *(const f16x8*)&wl[c * 16 + lrow][32 + lk];
            acc[c] = __builtin_amdgcn_mfma_f32_16x16x32_f16(a0, b0, acc[c], 0, 0, 0);
            acc[c] = __builtin_amdgcn_mfma_f32_16x16x32_f16(a1, b1, acc[c], 0, 0, 0);
        }
        __syncthreads();
    }
    int orow0 = row_base + (w << 4) + ((lane >> 4) << 2);
#pragma unroll
    for (int c = 0; c < 4; ++c) {
#pragma unroll
        for (int i = 0; i < 4; ++i) {
            int row = orow0 + i;
            if (row < NN) hb[(size_t)row * HID + c * 16 + lrow] = __float2half(acc[c][i]);
        }
    }
}

// ---------------- parallel scan of 588 bucket totals ----------------
__global__ __launch_bounds__(256) void k_scan(const u32* __restrict__ bin_total,
                                              u32* __restrict__ binstart) {
    __shared__ u32 s[256];
    int t = threadIdx.x;
    u32 c[3]; u32 sum = 0;
#pragma unroll
    for (int k = 0; k < 3; ++k) {
        int i = t * 3 + k;
        c[k] = (i < NBIN) ? bin_total[i] : 0;
        sum += c[k];
    }
    s[t] = sum;
    __syncthreads();
    for (int d = 1; d < 256; d <<= 1) {
        u32 v = (t >= d) ? s[t - d] : 0;
        __syncthreads();
        s[t] += v;
        __syncthreads();
    }
    u32 run = s[t] - sum;
#pragma unroll
    for (int k = 0; k < 3; ++k) {
        int i = t * 3 + k;
        if (i < NBIN) binstart[i] = run;
        run += c[k];
    }
    if (t == 255) binstart[NBIN] = run;
}

// ---------------- scatter edges into bucket-contiguous regions ----------------
__global__ __launch_bounds__(256) void k_scatter(
        const int* __restrict__ ei1, const int* __restrict__ ei2, const int* __restrict__ ei3,
        const float* __restrict__ ew1, const float* __restrict__ ew2, const float* __restrict__ ew3,
        const u32* __restrict__ binstart, const u32* __restrict__ blockbase,
        u64* __restrict__ bucketed) {
    __shared__ u32 cur[NBKT];
    int cb  = blockIdx.x;
    int br  = cb / CBLK;
    int blk = cb - br * CBLK;
    const int*   ei = (br == 0) ? ei1 : (br == 1) ? ei2 : ei3;
    const float* ew = (br == 0) ? ew1 : (br == 1) ? ew2 : ew3;
    int t = threadIdx.x;
    for (int i = t; i < NBKT; i += 256) cur[i] = 0;
    __syncthreads();
    int e0 = blk * 2048;
#pragma unroll
    for (int k = 0; k < 8; ++k) {
        int e = e0 + k * 256 + t;
        if (e < EE) {
            u32 dst = (u32)ei[EE + e];
            u32 src = (u32)ei[e];
            u32 bkt = dst >> 8;
            u32 rnk = atomicAdd(&cur[bkt], 1u);
            u32 pos = binstart[br * NBKT + bkt] + blockbase[cb * NBKT + bkt] + rnk;
            bucketed[pos] = ((u64)__float_as_uint(ew[e]) << 32) | (src << 8) | (dst & 0xffu);
        }
    }
}

// ---------------- per-bucket: nodeinfo/dinv/CSR in LDS + h-prescale of owned rows ----------------
__global__ __launch_bounds__(256) void k_bucket(
        const u64* __restrict__ bucketed, const u32* __restrict__ bin_total,
        const u32* __restrict__ binstart,
        u32* __restrict__ nodeinfo, float* __restrict__ dinv,
        u32* __restrict__ csr, __half* __restrict__ h) {
    __shared__ u32   scnt[256];
    __shared__ float swsum[256];
    __shared__ u32   scur[256];
    __shared__ u32   sscan[256];
    __shared__ float sdiv[256];
    __shared__ u32   lcsr[MAXB];
    int bin = blockIdx.x;
    int br  = bin / NBKT;
    int bkt = bin - br * NBKT;
    int t = threadIdx.x;
    u32 base = binstart[bin];
    u32 ecnt = bin_total[bin];
    scnt[t] = 0; swsum[t] = 0.f; scur[t] = 0;
    __syncthreads();
    for (u32 i = t; i < ecnt; i += 256) {
        u64 e = bucketed[base + i];
        u32 dl = (u32)e & 0xffu;
        atomicAdd(&scnt[dl], 1u);
        atomicAdd(&swsum[dl], __uint_as_float((u32)(e >> 32)));
    }
    __syncthreads();
    sscan[t] = scnt[t];
    __syncthreads();
    for (int d = 1; d < 256; d <<= 1) {
        u32 v = (t >= d) ? sscan[t - d] : 0;
        __syncthreads();
        sscan[t] += v;
        __syncthreads();
    }
    u32 lstart = sscan[t] - scnt[t];
    float d = rsqrtf(1.0f + swsum[t]);
    sdiv[t] = d;
    int n = bkt * 256 + t;
    if (n < NN) {
        int gi = br * NN + n;
        nodeinfo[gi] = ((base + lstart) << 10) | scnt[t];
        dinv[gi]     = d;
    }
    __syncthreads();
    for (u32 i = t; i < ecnt; i += 256) {
        u64 e = bucketed[base + i];
        u32 dl  = (u32)e & 0xffu;
        u32 src = (u32)(e >> 8) & 0xffffu;
        float w = __uint_as_float((u32)(e >> 32));
        u32 rnk = atomicAdd(&scur[dl], 1u);
        u32 ls  = sscan[dl] - scnt[dl];
        lcsr[ls + rnk] = ((u32)__half_as_ushort(__float2half(w)) << 16) | src;
    }
    __syncthreads();
    for (u32 i = t; i < ecnt; i += 256) csr[base + i] = lcsr[i];

    int nrows = NN - bkt * 256; if (nrows > 256) nrows = 256;
    u32* hrow = (u32*)(h + ((size_t)br * NN + (size_t)bkt * 256) * HID);
    for (int i = t; i < nrows * 32; i += 256) {
        float dd = sdiv[i >> 5];
        __half2 hv = *(__half2*)&hrow[i];
        float2 v = __half22float2(hv);
        __half2 r = __float22half2_rn(make_float2(v.x * dd, v.y * dd));
        hrow[i] = *(u32*)&r;
    }
}

// ---------------- layer-1 aggregation, BRANCH-MAJOR (L2 phase residency): e = ReLU(...) ----------------
__global__ __launch_bounds__(256) void k_agg1(
        const u32* __restrict__ csr, const u32* __restrict__ nodeinfo,
        const float* __restrict__ dinv,
        const float* __restrict__ b1, const float* __restrict__ b2, const float* __restrict__ b3,
        const __half* __restrict__ h, __half* __restrict__ e) {
    int bid = blockIdx.x;                    // branch-major: br phases of 12500 blocks
    int br  = bid / NBLK;
    int nb  = bid - br * NBLK;
    int t   = threadIdx.x;
    int f2  = t & 31;
    int eo  = (t >> 5) & 1;
    int sub = __builtin_amdgcn_readfirstlane(t >> 6);
    int n   = nb * 4 + sub;

    const float* bi = (br == 0) ? b1 : (br == 1) ? b2 : b3;
    const __half2* hb2 = (const __half2*)(h + (size_t)br * NN * HID);
    int i   = br * NN + n;
    u32 inf = nodeinfo[i];
    int cc  = (int)(inf & 1023u);
    int st  = (int)(inf >> 10);
    float d = dinv[i];
    float2 hs = __half22float2(hb2[(size_t)n * 32 + f2]);

    float ax = 0.f, ay = 0.f;
    int cm1 = cc - 1;
    for (int j = 0; j < cc; j += 16) {
        u32 ee[8]; __half2 vv[8];
#pragma unroll
        for (int u = 0; u < 8; ++u) {
            int jj = j + 2 * u + eo;
            ee[u] = csr[st + (jj < cm1 ? jj : cm1)];
            if (jj >= cc) ee[u] &= 0xffffu;
        }
#pragma unroll
        for (int u = 0; u < 8; ++u)
            vv[u] = hb2[(size_t)(ee[u] & 0xffff) * 32 + f2];
#pragma unroll
        for (int u = 0; u < 8; ++u) {
            float w = __half2float(__ushort_as_half((u16)(ee[u] >> 16)));
            float2 v = __half22float2(vv[u]);
            ax = fmaf(w, v.x, ax);
            ay = fmaf(w, v.y, ay);
        }
    }
    ax += __shfl_xor(ax, 32);
    ay += __shfl_xor(ay, 32);
    float2 bv = ((const float2*)bi)[f2];
    float ex = fmaxf(bv.x + d * (hs.x + ax), 0.f);
    float ey = fmaxf(bv.y + d * (hs.y + ay), 0.f);
    if (eo == 0)
        ((__half2*)e)[((size_t)br * NN + n) * 32 + f2] = __float22half2_rn(make_float2(ex, ey));
}

// ---------------- attention: coefs + comb from e (sequential reads) ----------------
__global__ __launch_bounds__(256) void k_attn(
        const __half* __restrict__ e,
        const float* __restrict__ fc_w, const float* __restrict__ fc_b,
        __half* __restrict__ comb, float* __restrict__ coef_out) {
    int t    = threadIdx.x;
    int lane = t & 63;
    int sub  = __builtin_amdgcn_readfirstlane(t >> 6);
    int half = lane >> 5;                  // 2 nodes per wave
    int f2   = lane & 31;
    int n    = blockIdx.x * 8 + sub * 2 + half;   // 50000 = 6250*8 exact
    float2 wv = ((const float2*)fc_w)[f2];
    float fb = fc_b[0];
    const __half2* e2 = (const __half2*)e;

    float2 ev[3]; float c[3];
#pragma unroll
    for (int b = 0; b < 3; ++b) {
        ev[b] = __half22float2(e2[((size_t)b * NN + n) * 32 + f2]);
        float dd = ev[b].x * wv.x + ev[b].y * wv.y;
#pragma unroll
        for (int off = 16; off > 0; off >>= 1) dd += __shfl_xor(dd, off);
        float z = dd + fb;
        z = (z > 0.f) ? z : 0.01f * z;
        c[b] = expf(z);
    }
    float cd = c[0] + c[1] + c[2];
    float coef0 = c[0] / cd, coef1 = c[1] / cd, coef2 = c[2] / cd;
    float cx = ev[0].x * coef0 + ev[1].x * coef1 + ev[2].x * coef2;
    float cy = ev[0].y * coef0 + ev[1].y * coef1 + ev[2].y * coef2;
    ((__half2*)comb)[(size_t)n * 32 + f2] = __float22half2_rn(make_float2(cx, cy));
    if (f2 == 0) {
        coef_out[n]          = coef0;
        coef_out[NN + n]     = coef1;
        coef_out[2 * NN + n] = coef2;
    }
}

// ---------------- layer-2 GEMM: h2'[b] = dinv * (comb @ W_b) ----------------
__global__ __launch_bounds__(256) void k_gemm2(
        const __half* __restrict__ comb,
        const float* __restrict__ W11, const float* __restrict__ W22, const float* __restrict__ W33,
        const float* __restrict__ dinv, __half* __restrict__ h2) {
    __shared__ float Wls[3][HID][OUTF];
    __shared__ __half cl[8][HID];
    int t = threadIdx.x;
    {
        const float4* w40 = reinterpret_cast<const float4*>(W11);
        const float4* w41 = reinterpret_cast<const float4*>(W22);
        const float4* w42 = reinterpret_cast<const float4*>(W33);
        float4* d0 = reinterpret_cast<float4*>(&Wls[0][0][0]);
        float4* d1 = reinterpret_cast<float4*>(&Wls[1][0][0]);
        float4* d2 = reinterpret_cast<float4*>(&Wls[2][0][0]);
#pragma unroll
        for (int j = 0; j < 2; ++j) {
            d0[t + j * 256] = w40[t + j * 256];
            d1[t + j * 256] = w41[t + j * 256];
            d2[t + j * 256] = w42[t + j * 256];
        }
    }
    int row0 = blockIdx.x * 8;
    ((u32*)cl)[t] = ((const u32*)(comb + (size_t)row0 * HID))[t];
    __syncthreads();

    int col = t & 31;
    int rr  = t >> 5;
    int row = row0 + rr;
    float a0 = 0.f, a1 = 0.f, a2 = 0.f;
    for (int k = 0; k < HID; ++k) {
        float cv = __half2float(cl[rr][k]);
        a0 = fmaf(cv, Wls[0][k][col], a0);
        a1 = fmaf(cv, Wls[1][k][col], a1);
        a2 = fmaf(cv, Wls[2][k][col], a2);
    }
    float d0 = dinv[row], d1 = dinv[NN + row], d2 = dinv[2 * NN + row];
    h2[(size_t)0 * NN * OUTF + (size_t)row * OUTF + col] = __float2half(a0 * d0);
    h2[(size_t)1 * NN * OUTF + (size_t)row * OUTF + col] = __float2half(a1 * d1);
    h2[(size_t)2 * NN * OUTF + (size_t)row * OUTF + col] = __float2half(a2 * d2);
}

// ---------------- layer-2 aggregation, BRANCH-MAJOR: partial sums to outp[br] ----------------
__global__ __launch_bounds__(256) void k_agg2p(
        const u32* __restrict__ csr, const u32* __restrict__ nodeinfo,
        const float* __restrict__ dinv,
        const __half* __restrict__ h2, float* __restrict__ outp) {
    int bid = blockIdx.x;
    int br  = bid / NBLK;
    int nb  = bid - br * NBLK;
    int t   = threadIdx.x;
    int f2  = t & 15;
    int eo  = (t >> 4) & 3;
    int sub = __builtin_amdgcn_readfirstlane(t >> 6);
    int n   = nb * 4 + sub;

    int i   = br * NN + n;
    u32 inf = nodeinfo[i];
    int cc  = (int)(inf & 1023u);
    int st  = (int)(inf >> 10);
    const __half2* h2b = (const __half2*)(h2 + (size_t)br * NN * OUTF);
    float ax = 0.f, ay = 0.f;
    int cm1 = cc - 1;
    for (int j = 0; j < cc; j += 16) {
        u32 ee[4]; __half2 vv[4];
#pragma unroll
        for (int u = 0; u < 4; ++u) {
            int jj = j + 4 * u + eo;
            ee[u] = csr[st + (jj < cm1 ? jj : cm1)];
            if (jj >= cc) ee[u] &= 0xffffu;
        }
#pragma unroll
        for (int u = 0; u < 4; ++u)
            vv[u] = h2b[(size_t)(ee[u] & 0xffff) * 16 + f2];
#pragma unroll
        for (int u = 0; u < 4; ++u) {
            float w = __half2float(__ushort_as_half((u16)(ee[u] >> 16)));
            float2 v = __half22float2(vv[u]);
            ax = fmaf(w, v.x, ax);
            ay = fmaf(w, v.y, ay);
        }
    }
    ax += __shfl_xor(ax, 16); ay += __shfl_xor(ay, 16);
    ax += __shfl_xor(ax, 32); ay += __shfl_xor(ay, 32);
    float d = dinv[i];
    float2 hs = __half22float2(h2b[(size_t)n * 16 + f2]);
    if (eo == 0)
        ((float2*)outp)[((size_t)br * NN + n) * 16 + f2] =
            make_float2(d * (ax + hs.x), d * (ay + hs.y));
}

// ---------------- final sum: out = outp0+outp1+outp2 + (b11+b22+b33) ----------------
__global__ __launch_bounds__(256) void k_sum(
        const float* __restrict__ outp,
        const float* __restrict__ b11, const float* __restrict__ b22, const float* __restrict__ b33,
        float* __restrict__ out) {
    int i = blockIdx.x * 256 + threadIdx.x;       // float2 units: 50000*16 = 3125*256 exact
    int f2 = i & 15;
    const float2* p = (const float2*)outp;
    float2 v0 = p[i];
    float2 v1 = p[(size_t)NN * 16 + i];
    float2 v2 = p[(size_t)2 * NN * 16 + i];
    float2 bA = ((const float2*)b11)[f2];
    float2 bB = ((const float2*)b22)[f2];
    float2 bC = ((const float2*)b33)[f2];
    ((float2*)out)[i] = make_float2(v0.x + v1.x + v2.x + bA.x + bB.x + bC.x,
                                    v0.y + v1.y + v2.y + bA.y + bB.y + bC.y);
}

// ---------------- launch ----------------
extern "C" void kernel_launch(void* const* d_in, const int* in_sizes, int n_in,
                              void* d_out, int out_size, void* d_ws, size_t ws_size,
                              hipStream_t stream) {
    const float* x1  = (const float*)d_in[0];
    const float* x2  = (const float*)d_in[1];
    const float* x3  = (const float*)d_in[2];
    const int*   ei1 = (const int*)d_in[3];
    const int*   ei2 = (const int*)d_in[4];
    const int*   ei3 = (const int*)d_in[5];
    const float* ew1 = (const float*)d_in[6];
    const float* ew2 = (const float*)d_in[7];
    const float* ew3 = (const float*)d_in[8];
    const float* W1  = (const float*)d_in[9];
    const float* W2  = (const float*)d_in[10];
    const float* W3  = (const float*)d_in[11];
    const float* b1  = (const float*)d_in[12];
    const float* b2  = (const float*)d_in[13];
    const float* b3  = (const float*)d_in[14];
    const float* fcw = (const float*)d_in[15];
    const float* fcb = (const float*)d_in[16];
    const float* W11 = (const float*)d_in[17];
    const float* W22 = (const float*)d_in[18];
    const float* W33 = (const float*)d_in[19];
    const float* b11 = (const float*)d_in[20];
    const float* b22 = (const float*)d_in[21];
    const float* b33 = (const float*)d_in[22];

    float* out = (float*)d_out;
    float* coef_out = out + (size_t)NN * OUTF;

    // workspace layout; outp aliases bucketed (dead after k_bucket)
    u64*   bucketed  = (u64*)d_ws;                           // 3E u64   19.2 MB
    float* outp      = (float*)d_ws;                         // 3N*32 f32 19.2 MB (alias)
    u32*   csr       = (u32*)(bucketed + 3 * EE);            // 3E u32    9.6 MB
    u32*   bin_total = csr + 3 * EE;                         // 588
    u32*   binstart  = bin_total + NBIN;                     // 592
    u32*   blockbase = binstart + NBIN + 4;                  // 1176*196
    float* dinv      = (float*)(blockbase + NCNT * NBKT);    // 3N
    u32*   nodeinfo  = (u32*)(dinv + TOTN);                  // 3N
    f16*   Wt        = (f16*)(nodeinfo + TOTN);              // 3*64*256
    __half* h        = (__half*)(Wt + 3 * HID * INF_);       // 3N*64    19.2 MB
    __half* comb     = h + (size_t)TOTN * HID;               // N*64      6.4 MB
    __half* h2       = comb + (size_t)NN * HID;              // 3N*32     9.6 MB
    __half* e        = h2 + (size_t)TOTN * OUTF;             // 3N*64    19.2 MB

    k_prep<<<dim3(4), 256, 0, stream>>>(W1, W2, W3, Wt, bin_total);
    k_cntgemm<<<dim3(NCNT * 3), 256, 0, stream>>>(ei1, ei2, ei3, bin_total, blockbase,
                                                  x1, x2, x3, Wt, h);
    k_scan<<<dim3(1), 256, 0, stream>>>(bin_total, binstart);
    k_scatter<<<dim3(NCNT), 256, 0, stream>>>(ei1, ei2, ei3, ew1, ew2, ew3,
                                              binstart, blockbase, bucketed);
    k_bucket<<<dim3(NBIN), 256, 0, stream>>>(bucketed, bin_total, binstart,
                                             nodeinfo, dinv, csr, h);

    k_agg1<<<dim3(3 * NBLK), 256, 0, stream>>>(csr, nodeinfo, dinv, b1, b2, b3, h, e);
    k_attn<<<dim3(NN / 8), 256, 0, stream>>>(e, fcw, fcb, comb, coef_out);
    k_gemm2<<<dim3(NN / 8), 256, 0, stream>>>(comb, W11, W22, W33, dinv, h2);
    k_agg2p<<<dim3(3 * NBLK), 256, 0, stream>>>(csr, nodeinfo, dinv, h2, outp);
    k_sum<<<dim3(3125), 256, 0, stream>>>(outp, b11, b22, b33, out);
}